// Round 8
// baseline (766.116 us; speedup 1.0000x reference)
//
#include <hip/hip_runtime.h>
#include <cstdint>

// AttCM R7: pass2 t-tile 64 -> 32. Diagnosis: grid (512 blocks) capped
// occupancy at 2 blocks/CU; per-CU floors (MFMA 66us, LDS 66us, L2 60us)
// were serializing. Now grid 1024 = 4 blocks/CU = 16 waves/CU; LDS 32KB
// (Q 16 + P dbuf 16). Everything else unchanged from R6.
// Shapes: B=8, C=256, HW=4096.

#define HW 4096
#define NB 8

typedef __attribute__((ext_vector_type(8))) _Float16 half8;    // 8 fp16 = 4 VGPR
typedef __attribute__((ext_vector_type(4))) float f32x4;       // MFMA C/D

static __device__ __forceinline__ unsigned short f2h(float x) {
  _Float16 h = (_Float16)x;
  return __builtin_bit_cast(unsigned short, h);
}

// ---------------- 1x1 weights fp32 -> fp16, all six packed ----------------
__global__ __launch_bounds__(256) void wcvt6(
    const float* __restrict__ w1, const float* __restrict__ w2,
    const float* __restrict__ w3, const float* __restrict__ wq,
    const float* __restrict__ wk, const float* __restrict__ wv,
    unsigned short* __restrict__ dst) {
  int i = blockIdx.x * 256 + threadIdx.x;
  const float* src; int off;
  if      (i <  16384) { src = w1; off = 0; }
  else if (i <  24576) { src = w2; off = 16384; }
  else if (i <  57344) { src = w3; off = 24576; }
  else if (i < 122880) { src = wq; off = 57344; }
  else if (i < 188416) { src = wk; off = 122880; }
  else                 { src = wv; off = 188416; }
  dst[i] = f2h(src[i - off]);
}

// ---------------- conv weight reorder: OIHW fp32 -> [o][tap][c] fp16 --------
__global__ __launch_bounds__(256) void wreorder(
    const float* __restrict__ w, unsigned short* __restrict__ wA) {
  const int o = blockIdx.x;
  const int c = threadIdx.x;
  const float* wp = w + ((size_t)o * 256 + c) * 9;
#pragma unroll
  for (int tap = 0; tap < 9; tap++)
    wA[((size_t)o * 9 + tap) * 256 + c] = f2h(wp[tap]);
}

// ---------------- fp32 [b][c][p] -> fp16 transposed [b][p][c] ----------------
__global__ __launch_bounds__(256) void transpose_cvt_h(
    const float* __restrict__ in, unsigned short* __restrict__ outT) {
  __shared__ float Ts[64][65];
  const int b  = blockIdx.x;
  const int t0 = blockIdx.y * 64;
  const int c0 = blockIdx.z * 64;
  const int tid = threadIdx.x;
#pragma unroll
  for (int it = 0; it < 4; it++) {
    int id = tid + it * 256;
    int c = id >> 4, f4 = id & 15;
    float4 v = *(const float4*)(in + ((size_t)(b * 256 + c0 + c)) * HW + t0 + f4 * 4);
    Ts[c][f4 * 4 + 0] = v.x; Ts[c][f4 * 4 + 1] = v.y;
    Ts[c][f4 * 4 + 2] = v.z; Ts[c][f4 * 4 + 3] = v.w;
  }
  __syncthreads();
#pragma unroll
  for (int it = 0; it < 2; it++) {
    int id = tid + it * 256;
    int t = id >> 3, ch = id & 7;
    unsigned short h[8];
#pragma unroll
    for (int e = 0; e < 8; e++) h[e] = f2h(Ts[ch * 8 + e][t]);
    int4 pk;
    pk.x = (int)((unsigned)h[0] | ((unsigned)h[1] << 16));
    pk.y = (int)((unsigned)h[2] | ((unsigned)h[3] << 16));
    pk.z = (int)((unsigned)h[4] | ((unsigned)h[5] << 16));
    pk.w = (int)((unsigned)h[6] | ((unsigned)h[7] << 16));
    ((int4*)outT)[((size_t)b * HW + t0 + t) * 32 + (c0 >> 3) + ch] = pk;
  }
}

// ---------------- 1x1 conv: fp16 MFMA GEMM, fused layout epilogue ----------
__global__ __launch_bounds__(256) void gemm1x1_h(
    const unsigned short* __restrict__ Wh,   // fp16 [M][K]
    const float* __restrict__ bias,
    const unsigned short* __restrict__ Xt,   // fp16 [b][4096][K]
    unsigned short* __restrict__ outT,
    unsigned short* __restrict__ outN,
    int K, int M, int mode, int doRelu) {
  __shared__ int4 WsL[64 * 32];
  __shared__ int4 XsL[128 * 8];
  const int b  = blockIdx.x;
  const int p0 = blockIdx.y * 256;
  const int m0 = blockIdx.z * 64;
  const int tid = threadIdx.x;
  const int w = tid >> 6, l = tid & 63;
  const int l4 = l >> 4, l15 = l & 15;
  const int KG  = K >> 3;
  const int kgl = (K >= 256) ? 5 : (K >= 128) ? 4 : 3;
  const int4* Wh4 = (const int4*)Wh;
  const int4* Xt4 = (const int4*)Xt + (size_t)(b * 4096 + p0) * KG;
  for (int id = tid; id < 64 * KG; id += 256) {
    int row = id >> kgl, g = id & (KG - 1);
    WsL[row * KG + (g ^ (row & 7))] = Wh4[(size_t)(m0 + row) * KG + g];
  }
  f32x4 acc[4][4];
#pragma unroll
  for (int i = 0; i < 4; i++)
#pragma unroll
    for (int j = 0; j < 4; j++) acc[i][j] = {0.f, 0.f, 0.f, 0.f};
  const int NCC = K >> 5;
  for (int cc = 0; cc < NCC; cc++) {
    __syncthreads();
#pragma unroll
    for (int it = 0; it < 4; it++) {
      int id = tid + it * 256;
      int p = id >> 2, ch = id & 3;
      XsL[(p >> 1) * 8 + ((((p & 1) << 2) + ch) ^ ((p >> 1) & 7))] =
          Xt4[(size_t)p * KG + cc * 4 + ch];
    }
    __syncthreads();
    half8 a[4], bx[4];
#pragma unroll
    for (int mf = 0; mf < 4; mf++) {
      int m = mf * 16 + l15;
      a[mf] = ((const half8*)WsL)[m * KG + ((cc * 4 + l4) ^ (m & 7))];
    }
#pragma unroll
    for (int nf = 0; nf < 4; nf++) {
      int p = w * 64 + nf * 16 + l15;
      bx[nf] = ((const half8*)XsL)[(p >> 1) * 8 + ((((p & 1) << 2) + l4) ^ ((p >> 1) & 7))];
    }
#pragma unroll
    for (int mf = 0; mf < 4; mf++)
#pragma unroll
      for (int nf = 0; nf < 4; nf++)
        acc[mf][nf] = __builtin_amdgcn_mfma_f32_16x16x32_f16(a[mf], bx[nf], acc[mf][nf], 0, 0, 0);
  }
#pragma unroll
  for (int mf = 0; mf < 4; mf++) {
    const int mrow = m0 + mf * 16 + l4 * 4;
    const f32x4 bv = *(const f32x4*)(bias + mrow);
#pragma unroll
    for (int nf = 0; nf < 4; nf++) {
      const int p = p0 + w * 64 + nf * 16 + l15;
      float vr[4];
#pragma unroll
      for (int r = 0; r < 4; r++) {
        float v = acc[mf][nf][r] + bv[r];
        if (doRelu) v = fmaxf(v, 0.0f);
        vr[r] = v;
      }
      if (mode == 0) {
        unsigned long long pk = (unsigned long long)f2h(vr[0]) |
                                ((unsigned long long)f2h(vr[1]) << 16) |
                                ((unsigned long long)f2h(vr[2]) << 32) |
                                ((unsigned long long)f2h(vr[3]) << 48);
        *(unsigned long long*)(outT + ((size_t)b * 4096 + p) * M + mrow) = pk;
      } else {
#pragma unroll
        for (int r = 0; r < 4; r++)
          outN[((size_t)(b * M + mrow + r)) * 4096 + p] = f2h(vr[r]);
      }
    }
  }
}

// ---------------- 3x3 conv, fp16 MFMA implicit GEMM (unchanged) ------------
__global__ __launch_bounds__(256, 2) void conv3x3_mfma(
    const unsigned short* __restrict__ inT,
    const unsigned short* __restrict__ wA,
    const float* __restrict__ bias,
    unsigned short* __restrict__ outT,
    float* __restrict__ outN,
    int mode) {
  __shared__ int4 wS[2304];
  __shared__ int4 inS[1584];
  const int b  = blockIdx.x;
  const int y0 = blockIdx.y * 4;
  const int o0 = blockIdx.z * 64;
  const int tid = threadIdx.x;
  const int w = tid >> 6, l = tid & 63;
  const int l4 = l >> 4, l15 = l & 15;
  const int4* inT4 = (const int4*)inT + (size_t)b * 4096 * 32;
  const int4* wA4  = (const int4*)wA;
  f32x4 acc[4][4];
#pragma unroll
  for (int i = 0; i < 4; i++)
#pragma unroll
    for (int j = 0; j < 4; j++) acc[i][j] = {0.f, 0.f, 0.f, 0.f};

  for (int c0 = 0; c0 < 256; c0 += 32) {
    __syncthreads();
#pragma unroll
    for (int it = 0; it < 9; it++) {
      int id = it * 256 + tid;
      int ch = id & 3;
      int r  = id >> 2;
      int tap = r % 9, ol = r / 9;
      int sbw = tap * 32 + (ol >> 1);
      int slot = (4 * (ol & 1) + ch) ^ (sbw & 7);
      wS[sbw * 8 + slot] = wA4[((size_t)(o0 + ol) * 9 + tap) * 32 + (c0 >> 3) + ch];
    }
#pragma unroll
    for (int it = 0; it < 6; it++) {
      int ch = tid & 3;
      int col = tid >> 2;
      int yimg = y0 + it - 1;
      int4 v = {0, 0, 0, 0};
      if (yimg >= 0 && yimg < 64)
        v = inT4[(size_t)(yimg * 64 + col) * 32 + (c0 >> 3) + ch];
      int cl = col + 1;
      int sb = it * 33 + (cl >> 1);
      int slot = (4 * (cl & 1) + ch) ^ (sb & 7);
      inS[sb * 8 + slot] = v;
    }
    if (tid < 48) {
      int row = tid >> 3;
      int cl = ((tid >> 2) & 1) ? 65 : 0;
      int ch = tid & 3;
      int sb = row * 33 + (cl >> 1);
      int slot = (4 * (cl & 1) + ch) ^ (sb & 7);
      inS[sb * 8 + slot] = {0, 0, 0, 0};
    }
    __syncthreads();
#pragma unroll
    for (int tap = 0; tap < 9; tap++) {
      const int dy = tap / 3, dx = tap % 3;
      half8 a[4], bf[4];
#pragma unroll
      for (int mf = 0; mf < 4; mf++) {
        int oc = mf * 16 + l15;
        int sbw = tap * 32 + (oc >> 1);
        a[mf] = ((const half8*)wS)[sbw * 8 + ((4 * (oc & 1) + l4) ^ (sbw & 7))];
      }
#pragma unroll
      for (int nf = 0; nf < 4; nf++) {
        int cl = nf * 16 + l15 + dx;
        int row = w + dy;
        int sb = row * 33 + (cl >> 1);
        bf[nf] = ((const half8*)inS)[sb * 8 + ((4 * (cl & 1) + l4) ^ (sb & 7))];
      }
#pragma unroll
      for (int mf = 0; mf < 4; mf++)
#pragma unroll
        for (int nf = 0; nf < 4; nf++)
          acc[mf][nf] = __builtin_amdgcn_mfma_f32_16x16x32_f16(a[mf], bf[nf], acc[mf][nf], 0, 0, 0);
    }
  }
  const int p_base = (y0 + w) * 64;
#pragma unroll
  for (int mf = 0; mf < 4; mf++) {
    const int ocb = o0 + mf * 16 + l4 * 4;
    const f32x4 bv = *(const f32x4*)(bias + ocb);
#pragma unroll
    for (int nf = 0; nf < 4; nf++) {
      const int p = p_base + nf * 16 + l15;
      if (mode == 0) {
        unsigned short h[4];
#pragma unroll
        for (int r = 0; r < 4; r++)
          h[r] = f2h(fmaxf(acc[mf][nf][r] + bv[r], 0.0f));
        unsigned long long pk = (unsigned long long)h[0] |
                                ((unsigned long long)h[1] << 16) |
                                ((unsigned long long)h[2] << 32) |
                                ((unsigned long long)h[3] << 48);
        *(unsigned long long*)(outT + ((size_t)b * 4096 + p) * 256 + ocb) = pk;
      } else {
#pragma unroll
        for (int r = 0; r < 4; r++)
          outN[((size_t)(b * 256 + ocb + r)) * HW + p] = acc[mf][nf][r] + bv[r];
      }
    }
  }
}

// ---------------- attention pass 1a: partial row stats over a t-quarter -----
__global__ __launch_bounds__(256, 4) void attn_rowstats_part(
    const unsigned short* __restrict__ kT, const unsigned short* __restrict__ qT,
    float* __restrict__ Mp, float* __restrict__ Zp) {
  __shared__ int4 qs4[64][32];   // 32KB [t][c-granule], swizzled
  const int b  = blockIdx.x;
  const int r0 = blockIdx.y * 64;
  const int q  = blockIdx.z;
  const int tid = threadIdx.x;
  const int w = tid >> 6, l = tid & 63;
  const int l4 = l >> 4, l15 = l & 15;
  const int4* qT4 = (const int4*)qT + (size_t)b * HW * 32;
  const half8* kT8 = (const half8*)kT + ((size_t)b * HW + r0) * 32;
  half8 afr[8];                  // wave w owns rows [w*16, w*16+16)
#pragma unroll
  for (int ks = 0; ks < 8; ks++)
    afr[ks] = kT8[(size_t)(w * 16 + l15) * 32 + ks * 4 + l4];
  float m[4], z[4];
#pragma unroll
  for (int i = 0; i < 4; i++) { m[i] = -1e30f; z[i] = 0.0f; }
  for (int t0 = q * 1024; t0 < q * 1024 + 1024; t0 += 64) {
    __syncthreads();
#pragma unroll
    for (int it = 0; it < 8; it++) {
      int id = tid + it * 256;
      int row = id >> 5, ch = id & 31;
      qs4[row][ch ^ (row & 7)] = qT4[(size_t)(t0 + row) * 32 + ch];
    }
    __syncthreads();
    f32x4 acc[4] = {{0.f,0.f,0.f,0.f},{0.f,0.f,0.f,0.f},
                    {0.f,0.f,0.f,0.f},{0.f,0.f,0.f,0.f}};
#pragma unroll
    for (int ks = 0; ks < 8; ks++) {
#pragma unroll
      for (int nf = 0; nf < 4; nf++) {
        int t = nf * 16 + l15;
        half8 bq = ((const half8*)qs4)[t * 32 + ((ks * 4 + l4) ^ (t & 7))];
        acc[nf] = __builtin_amdgcn_mfma_f32_16x16x32_f16(afr[ks], bq, acc[nf], 0, 0, 0);
      }
    }
#pragma unroll
    for (int nf = 0; nf < 4; nf++)
#pragma unroll
      for (int r = 0; r < 4; r++) {
        float sv = acc[nf][r];
        if (sv > m[r]) { z[r] *= __expf(m[r] - sv); m[r] = sv; }
        z[r] += __expf(sv - m[r]);
      }
  }
#pragma unroll
  for (int r = 0; r < 4; r++) {
    for (int off = 1; off < 16; off <<= 1) {
      float mo = __shfl_xor(m[r], off, 16);
      float zo = __shfl_xor(z[r], off, 16);
      float mn = fmaxf(m[r], mo);
      z[r] = z[r] * __expf(m[r] - mn) + zo * __expf(mo - mn);
      m[r] = mn;
    }
  }
  if (l15 == 0) {
#pragma unroll
    for (int r = 0; r < 4; r++) {
      int rr = r0 + w * 16 + l4 * 4 + r;
      Mp[((size_t)b * HW + rr) * 4 + q] = m[r];
      Zp[((size_t)b * HW + rr) * 4 + q] = z[r];
    }
  }
}

// ---------------- attention pass 1b: merge 4 quarters -----------------------
__global__ __launch_bounds__(256) void reduce_mz(
    const float* __restrict__ Mp, const float* __restrict__ Zp,
    float* __restrict__ Mrow, float* __restrict__ Zrow) {
  int i = blockIdx.x * 256 + threadIdx.x;      // 0 .. 8*4096-1
  float4 mq = *(const float4*)(Mp + (size_t)i * 4);
  float4 zq = *(const float4*)(Zp + (size_t)i * 4);
  float M = fmaxf(fmaxf(mq.x, mq.y), fmaxf(mq.z, mq.w));
  float Z = zq.x * __expf(mq.x - M) + zq.y * __expf(mq.y - M)
          + zq.z * __expf(mq.z - M) + zq.w * __expf(mq.w - M);
  Mrow[i] = M;
  Zrow[i] = 1.0f / Z;
}

// ---------------- attention pass 2: t-tile 32, 4 blocks/CU ------------------
__global__ __launch_bounds__(256, 4) void attn_pass2(
    const unsigned short* __restrict__ kT, const unsigned short* __restrict__ qT,
    const unsigned short* __restrict__ vB, const float* __restrict__ Mrow,
    const float* __restrict__ Zrow, const float* __restrict__ alphap,
    const float* __restrict__ betap, float* __restrict__ out) {
  __shared__ int4 qs4[32][32];      // 16KB Q [t][c-granule], swizzled
  __shared__ int4 ps4[2][32][16];   // 2x8KB P [t][r-granule], swizzled
  const int b  = blockIdx.x;
  const int t0 = blockIdx.y * 32;
  const int tid = threadIdx.x;
  const int w = tid >> 6, l = tid & 63;
  const int l4 = l >> 4, l15 = l & 15;
  const int4*  qT4 = (const int4*)qT + ((size_t)b * HW + t0) * 32;
  const half8* kT8 = (const half8*)kT + (size_t)b * HW * 32;
  const half8* vB8 = (const half8*)vB + (size_t)b * 256 * 512;
  const float* Mb = Mrow + (size_t)b * HW;
  const float* Zb = Zrow + (size_t)b * HW;
  // stage Q once (swizzled): 32 rows x 32 granules = 1024 int4
#pragma unroll
  for (int it = 0; it < 4; it++) {
    int id = tid + it * 256;
    int row = id >> 5, ch = id & 31;
    qs4[row][ch ^ (row & 7)] = qT4[(size_t)row * 32 + ch];
  }
  f32x4 acc_o[4][2];               // [cc4][nf]
#pragma unroll
  for (int i = 0; i < 4; i++)
#pragma unroll
    for (int j = 0; j < 2; j++) acc_o[i][j] = {0.f, 0.f, 0.f, 0.f};
  __syncthreads();

#pragma unroll 1
  for (int iter = 0; iter < 32; iter++) {
    const int r0 = iter * 128;
    int4* psb = &ps4[iter & 1][0][0];
    // ---- K rows -> regs (wave w owns rows [w*32, w*32+32))
    half8 ak0[8], ak1[8];
#pragma unroll
    for (int g = 0; g < 8; g++) {
      ak0[g] = kT8[(size_t)(r0 + w * 32 + l15) * 32 + g * 4 + l4];
      ak1[g] = kT8[(size_t)(r0 + w * 32 + 16 + l15) * 32 + g * 4 + l4];
    }
    // ---- S phase: S[128r][32t] (Q read-only in LDS, no barrier)
    f32x4 acc_s[2][2];
#pragma unroll
    for (int i = 0; i < 2; i++)
#pragma unroll
      for (int j = 0; j < 2; j++) acc_s[i][j] = {0.f, 0.f, 0.f, 0.f};
#pragma unroll
    for (int g = 0; g < 8; g++) {
      half8 bq[2];
#pragma unroll
      for (int nf = 0; nf < 2; nf++) {
        int t = nf * 16 + l15;
        bq[nf] = ((const half8*)qs4)[t * 32 + ((g * 4 + l4) ^ (t & 7))];
      }
#pragma unroll
      for (int nf = 0; nf < 2; nf++) {
        acc_s[0][nf] = __builtin_amdgcn_mfma_f32_16x16x32_f16(ak0[g], bq[nf], acc_s[0][nf], 0, 0, 0);
        acc_s[1][nf] = __builtin_amdgcn_mfma_f32_16x16x32_f16(ak1[g], bq[nf], acc_s[1][nf], 0, 0, 0);
      }
    }
    // ---- V preload, first half (cc4 0,1)
    half8 avr[4][4];   // [cc4][ks]
#pragma unroll
    for (int cc4 = 0; cc4 < 2; cc4++) {
      const int c = cc4 * 64 + w * 16 + l15;
#pragma unroll
      for (int ks = 0; ks < 4; ks++)
        avr[cc4][ks] = vB8[(size_t)c * 512 + (r0 >> 3) + ks * 4 + l4];
    }
    // ---- P = exp(S - M_r) * rZ_r -> psb[t][r] packed fp16
#pragma unroll
    for (int mfl = 0; mfl < 2; mfl++) {
      int rbase = r0 + w * 32 + mfl * 16 + l4 * 4;
      f32x4 Mv = *(const f32x4*)(Mb + rbase);
      f32x4 Zv = *(const f32x4*)(Zb + rbase);
      int slot = w * 8 + mfl * 4 + l4;
#pragma unroll
      for (int nf = 0; nf < 2; nf++) {
        int t = nf * 16 + l15;
        unsigned lo = (unsigned)f2h(__expf(acc_s[mfl][nf][0] - Mv[0]) * Zv[0])
                    | ((unsigned)f2h(__expf(acc_s[mfl][nf][1] - Mv[1]) * Zv[1]) << 16);
        unsigned hi = (unsigned)f2h(__expf(acc_s[mfl][nf][2] - Mv[2]) * Zv[2])
                    | ((unsigned)f2h(__expf(acc_s[mfl][nf][3] - Mv[3]) * Zv[3]) << 16);
        int ch = slot >> 1;
        int fslot = ((ch ^ (t & 7)) << 1) | (slot & 1);
        ((unsigned long long*)psb)[(size_t)t * 32 + fslot] =
            ((unsigned long long)hi << 32) | (unsigned long long)lo;
      }
    }
    __syncthreads();   // P visible; prev-iter PV reads (other buffer) done
    // ---- V preload, second half (cc4 2,3)
#pragma unroll
    for (int cc4 = 2; cc4 < 4; cc4++) {
      const int c = cc4 * 64 + w * 16 + l15;
#pragma unroll
      for (int ks = 0; ks < 4; ks++)
        avr[cc4][ks] = vB8[(size_t)c * 512 + (r0 >> 3) + ks * 4 + l4];
    }
    // ---- PV: each P fragment LDS-read once, V from regs
#pragma unroll
    for (int ks = 0; ks < 4; ks++) {
#pragma unroll
      for (int nf = 0; nf < 2; nf++) {
        int t = nf * 16 + l15;
        half8 bp = ((const half8*)psb)[t * 16 + ((ks * 4 + l4) ^ (t & 7))];
#pragma unroll
        for (int cc4 = 0; cc4 < 4; cc4++)
          acc_o[cc4][nf] = __builtin_amdgcn_mfma_f32_16x16x32_f16(avr[cc4][ks], bp, acc_o[cc4][nf], 0, 0, 0);
      }
    }
  }
  // ---- epilogue: out = alpha*cb + beta*attn (cb already in out)
  const float alpha = alphap[0], beta = betap[0];
#pragma unroll
  for (int cc4 = 0; cc4 < 4; cc4++) {
    int cbase = cc4 * 64 + w * 16 + l4 * 4;
#pragma unroll
    for (int nf = 0; nf < 2; nf++) {
      int t = t0 + nf * 16 + l15;
#pragma unroll
      for (int r = 0; r < 4; r++) {
        size_t idx = ((size_t)(b * 256 + cbase + r)) * HW + t;
        out[idx] = alpha * out[idx] + beta * acc_o[cc4][nf][r];
      }
    }
  }
}

extern "C" void kernel_launch(void* const* d_in, const int* in_sizes, int n_in,
                              void* d_out, int out_size, void* d_ws, size_t ws_size,
                              hipStream_t stream) {
  (void)in_sizes; (void)n_in; (void)out_size; (void)ws_size;
  const float* x   = (const float*)d_in[0];
  const float* w1  = (const float*)d_in[1];
  const float* b1  = (const float*)d_in[2];
  const float* w2  = (const float*)d_in[3];
  const float* b2  = (const float*)d_in[4];
  const float* w3  = (const float*)d_in[5];
  const float* b3  = (const float*)d_in[6];
  const float* wb1 = (const float*)d_in[7];
  const float* bb1 = (const float*)d_in[8];
  const float* wb2 = (const float*)d_in[9];
  const float* bb2 = (const float*)d_in[10];
  const float* wq  = (const float*)d_in[11];
  const float* bq  = (const float*)d_in[12];
  const float* wk  = (const float*)d_in[13];
  const float* bk  = (const float*)d_in[14];
  const float* wv  = (const float*)d_in[15];
  const float* bv  = (const float*)d_in[16];
  const float* alpha = (const float*)d_in[17];
  const float* beta  = (const float*)d_in[18];
  float* out = (float*)d_out;

  const size_t SZH = (size_t)NB * 4096 * 256;   // 8,388,608 halves = 16MB
  unsigned short* wsh = (unsigned short*)d_ws;
  unsigned short* xh  = wsh;
  unsigned short* xfT = wsh + SZH;
  unsigned short* qT  = wsh + 2 * SZH;
  unsigned short* kT  = wsh + 3 * SZH;
  unsigned short* vN  = wsh + 4 * SZH;
  unsigned short* y1T = wsh + 5 * SZH;
  unsigned short* y2T = y1T + SZH / 4;
  unsigned short* t1T = wsh + 5 * SZH;
  float* Mrow = (float*)(wsh + 6 * SZH);
  float* Zrow = Mrow + (size_t)NB * HW;
  float* Mp   = Zrow + (size_t)NB * HW;         // [B*HW*4] partials
  float* Zp   = Mp + (size_t)NB * HW * 4;
  unsigned short* wh   = (unsigned short*)(Zp + (size_t)NB * HW * 4);
  unsigned short* w1h  = wh;
  unsigned short* w2h  = wh + 16384;
  unsigned short* w3h  = wh + 24576;
  unsigned short* wqh  = wh + 57344;
  unsigned short* wkh  = wh + 122880;
  unsigned short* wvh  = wh + 188416;
  unsigned short* wA1h = wh + 253952;
  unsigned short* wA2h = wA1h + (size_t)256 * 9 * 256;

  wcvt6<<<992, 256, 0, stream>>>(w1, w2, w3, wq, wk, wv, wh);
  wreorder<<<256, 256, 0, stream>>>(wb1, wA1h);
  wreorder<<<256, 256, 0, stream>>>(wb2, wA2h);
  transpose_cvt_h<<<dim3(8, 64, 4), 256, 0, stream>>>(x, xh);
  gemm1x1_h<<<dim3(8, 16, 1), 256, 0, stream>>>(w1h, b1, xh,  y1T, nullptr, 256,  64, 0, 1);
  gemm1x1_h<<<dim3(8, 16, 2), 256, 0, stream>>>(w2h, b2, y1T, y2T, nullptr,  64, 128, 0, 1);
  gemm1x1_h<<<dim3(8, 16, 4), 256, 0, stream>>>(w3h, b3, y2T, xfT, nullptr, 128, 256, 0, 1);
  gemm1x1_h<<<dim3(8, 16, 4), 256, 0, stream>>>(wqh, bq, xfT, qT,  nullptr, 256, 256, 0, 0);
  gemm1x1_h<<<dim3(8, 16, 4), 256, 0, stream>>>(wkh, bk, xfT, kT,  nullptr, 256, 256, 0, 0);
  gemm1x1_h<<<dim3(8, 16, 4), 256, 0, stream>>>(wvh, bv, xfT, nullptr, vN,  256, 256, 1, 0);
  conv3x3_mfma<<<dim3(8, 16, 4), 256, 0, stream>>>(xfT, wA1h, bb1, t1T, nullptr, 0);
  conv3x3_mfma<<<dim3(8, 16, 4), 256, 0, stream>>>(t1T, wA2h, bb2, nullptr, out, 1);
  attn_rowstats_part<<<dim3(8, 64, 4), 256, 0, stream>>>(kT, qT, Mp, Zp);
  reduce_mz<<<128, 256, 0, stream>>>(Mp, Zp, Mrow, Zrow);
  attn_pass2<<<dim3(8, 128), 256, 0, stream>>>(kT, qT, vN, Mrow, Zrow,
                                               alpha, beta, out);
}

// Round 9
// 584.452 us; speedup vs baseline: 1.3108x; 1.3108x over previous
//
#include <hip/hip_runtime.h>
#include <cstdint>

// AttCM R8: pass2 = R6 geometry (t-tile 64, proven best) + cross-iteration
// K-prefetch (double-buffered K regs, statically named A/B sets via 2x body).
// R7 lesson: per-iter critical path (K-load latency + exp + barrier) is the
// limit, not occupancy; prefetch hides the K-load leg. All else = R6.
// Shapes: B=8, C=256, HW=4096.

#define HW 4096
#define NB 8

typedef __attribute__((ext_vector_type(8))) _Float16 half8;    // 8 fp16 = 4 VGPR
typedef __attribute__((ext_vector_type(4))) float f32x4;       // MFMA C/D

static __device__ __forceinline__ unsigned short f2h(float x) {
  _Float16 h = (_Float16)x;
  return __builtin_bit_cast(unsigned short, h);
}

// ---------------- 1x1 weights fp32 -> fp16, all six packed ----------------
__global__ __launch_bounds__(256) void wcvt6(
    const float* __restrict__ w1, const float* __restrict__ w2,
    const float* __restrict__ w3, const float* __restrict__ wq,
    const float* __restrict__ wk, const float* __restrict__ wv,
    unsigned short* __restrict__ dst) {
  int i = blockIdx.x * 256 + threadIdx.x;
  const float* src; int off;
  if      (i <  16384) { src = w1; off = 0; }
  else if (i <  24576) { src = w2; off = 16384; }
  else if (i <  57344) { src = w3; off = 24576; }
  else if (i < 122880) { src = wq; off = 57344; }
  else if (i < 188416) { src = wk; off = 122880; }
  else                 { src = wv; off = 188416; }
  dst[i] = f2h(src[i - off]);
}

// ---------------- conv weight reorder: OIHW fp32 -> [o][tap][c] fp16 --------
__global__ __launch_bounds__(256) void wreorder(
    const float* __restrict__ w, unsigned short* __restrict__ wA) {
  const int o = blockIdx.x;
  const int c = threadIdx.x;
  const float* wp = w + ((size_t)o * 256 + c) * 9;
#pragma unroll
  for (int tap = 0; tap < 9; tap++)
    wA[((size_t)o * 9 + tap) * 256 + c] = f2h(wp[tap]);
}

// ---------------- fp32 [b][c][p] -> fp16 transposed [b][p][c] ----------------
__global__ __launch_bounds__(256) void transpose_cvt_h(
    const float* __restrict__ in, unsigned short* __restrict__ outT) {
  __shared__ float Ts[64][65];
  const int b  = blockIdx.x;
  const int t0 = blockIdx.y * 64;
  const int c0 = blockIdx.z * 64;
  const int tid = threadIdx.x;
#pragma unroll
  for (int it = 0; it < 4; it++) {
    int id = tid + it * 256;
    int c = id >> 4, f4 = id & 15;
    float4 v = *(const float4*)(in + ((size_t)(b * 256 + c0 + c)) * HW + t0 + f4 * 4);
    Ts[c][f4 * 4 + 0] = v.x; Ts[c][f4 * 4 + 1] = v.y;
    Ts[c][f4 * 4 + 2] = v.z; Ts[c][f4 * 4 + 3] = v.w;
  }
  __syncthreads();
#pragma unroll
  for (int it = 0; it < 2; it++) {
    int id = tid + it * 256;
    int t = id >> 3, ch = id & 7;
    unsigned short h[8];
#pragma unroll
    for (int e = 0; e < 8; e++) h[e] = f2h(Ts[ch * 8 + e][t]);
    int4 pk;
    pk.x = (int)((unsigned)h[0] | ((unsigned)h[1] << 16));
    pk.y = (int)((unsigned)h[2] | ((unsigned)h[3] << 16));
    pk.z = (int)((unsigned)h[4] | ((unsigned)h[5] << 16));
    pk.w = (int)((unsigned)h[6] | ((unsigned)h[7] << 16));
    ((int4*)outT)[((size_t)b * HW + t0 + t) * 32 + (c0 >> 3) + ch] = pk;
  }
}

// ---------------- 1x1 conv: fp16 MFMA GEMM, fused layout epilogue ----------
__global__ __launch_bounds__(256) void gemm1x1_h(
    const unsigned short* __restrict__ Wh,   // fp16 [M][K]
    const float* __restrict__ bias,
    const unsigned short* __restrict__ Xt,   // fp16 [b][4096][K]
    unsigned short* __restrict__ outT,
    unsigned short* __restrict__ outN,
    int K, int M, int mode, int doRelu) {
  __shared__ int4 WsL[64 * 32];
  __shared__ int4 XsL[128 * 8];
  const int b  = blockIdx.x;
  const int p0 = blockIdx.y * 256;
  const int m0 = blockIdx.z * 64;
  const int tid = threadIdx.x;
  const int w = tid >> 6, l = tid & 63;
  const int l4 = l >> 4, l15 = l & 15;
  const int KG  = K >> 3;
  const int kgl = (K >= 256) ? 5 : (K >= 128) ? 4 : 3;
  const int4* Wh4 = (const int4*)Wh;
  const int4* Xt4 = (const int4*)Xt + (size_t)(b * 4096 + p0) * KG;
  for (int id = tid; id < 64 * KG; id += 256) {
    int row = id >> kgl, g = id & (KG - 1);
    WsL[row * KG + (g ^ (row & 7))] = Wh4[(size_t)(m0 + row) * KG + g];
  }
  f32x4 acc[4][4];
#pragma unroll
  for (int i = 0; i < 4; i++)
#pragma unroll
    for (int j = 0; j < 4; j++) acc[i][j] = {0.f, 0.f, 0.f, 0.f};
  const int NCC = K >> 5;
  for (int cc = 0; cc < NCC; cc++) {
    __syncthreads();
#pragma unroll
    for (int it = 0; it < 4; it++) {
      int id = tid + it * 256;
      int p = id >> 2, ch = id & 3;
      XsL[(p >> 1) * 8 + ((((p & 1) << 2) + ch) ^ ((p >> 1) & 7))] =
          Xt4[(size_t)p * KG + cc * 4 + ch];
    }
    __syncthreads();
    half8 a[4], bx[4];
#pragma unroll
    for (int mf = 0; mf < 4; mf++) {
      int m = mf * 16 + l15;
      a[mf] = ((const half8*)WsL)[m * KG + ((cc * 4 + l4) ^ (m & 7))];
    }
#pragma unroll
    for (int nf = 0; nf < 4; nf++) {
      int p = w * 64 + nf * 16 + l15;
      bx[nf] = ((const half8*)XsL)[(p >> 1) * 8 + ((((p & 1) << 2) + l4) ^ ((p >> 1) & 7))];
    }
#pragma unroll
    for (int mf = 0; mf < 4; mf++)
#pragma unroll
      for (int nf = 0; nf < 4; nf++)
        acc[mf][nf] = __builtin_amdgcn_mfma_f32_16x16x32_f16(a[mf], bx[nf], acc[mf][nf], 0, 0, 0);
  }
#pragma unroll
  for (int mf = 0; mf < 4; mf++) {
    const int mrow = m0 + mf * 16 + l4 * 4;
    const f32x4 bv = *(const f32x4*)(bias + mrow);
#pragma unroll
    for (int nf = 0; nf < 4; nf++) {
      const int p = p0 + w * 64 + nf * 16 + l15;
      float vr[4];
#pragma unroll
      for (int r = 0; r < 4; r++) {
        float v = acc[mf][nf][r] + bv[r];
        if (doRelu) v = fmaxf(v, 0.0f);
        vr[r] = v;
      }
      if (mode == 0) {
        unsigned long long pk = (unsigned long long)f2h(vr[0]) |
                                ((unsigned long long)f2h(vr[1]) << 16) |
                                ((unsigned long long)f2h(vr[2]) << 32) |
                                ((unsigned long long)f2h(vr[3]) << 48);
        *(unsigned long long*)(outT + ((size_t)b * 4096 + p) * M + mrow) = pk;
      } else {
#pragma unroll
        for (int r = 0; r < 4; r++)
          outN[((size_t)(b * M + mrow + r)) * 4096 + p] = f2h(vr[r]);
      }
    }
  }
}

// ---------------- 3x3 conv, fp16 MFMA implicit GEMM (unchanged) ------------
__global__ __launch_bounds__(256, 2) void conv3x3_mfma(
    const unsigned short* __restrict__ inT,
    const unsigned short* __restrict__ wA,
    const float* __restrict__ bias,
    unsigned short* __restrict__ outT,
    float* __restrict__ outN,
    int mode) {
  __shared__ int4 wS[2304];
  __shared__ int4 inS[1584];
  const int b  = blockIdx.x;
  const int y0 = blockIdx.y * 4;
  const int o0 = blockIdx.z * 64;
  const int tid = threadIdx.x;
  const int w = tid >> 6, l = tid & 63;
  const int l4 = l >> 4, l15 = l & 15;
  const int4* inT4 = (const int4*)inT + (size_t)b * 4096 * 32;
  const int4* wA4  = (const int4*)wA;
  f32x4 acc[4][4];
#pragma unroll
  for (int i = 0; i < 4; i++)
#pragma unroll
    for (int j = 0; j < 4; j++) acc[i][j] = {0.f, 0.f, 0.f, 0.f};

  for (int c0 = 0; c0 < 256; c0 += 32) {
    __syncthreads();
#pragma unroll
    for (int it = 0; it < 9; it++) {
      int id = it * 256 + tid;
      int ch = id & 3;
      int r  = id >> 2;
      int tap = r % 9, ol = r / 9;
      int sbw = tap * 32 + (ol >> 1);
      int slot = (4 * (ol & 1) + ch) ^ (sbw & 7);
      wS[sbw * 8 + slot] = wA4[((size_t)(o0 + ol) * 9 + tap) * 32 + (c0 >> 3) + ch];
    }
#pragma unroll
    for (int it = 0; it < 6; it++) {
      int ch = tid & 3;
      int col = tid >> 2;
      int yimg = y0 + it - 1;
      int4 v = {0, 0, 0, 0};
      if (yimg >= 0 && yimg < 64)
        v = inT4[(size_t)(yimg * 64 + col) * 32 + (c0 >> 3) + ch];
      int cl = col + 1;
      int sb = it * 33 + (cl >> 1);
      int slot = (4 * (cl & 1) + ch) ^ (sb & 7);
      inS[sb * 8 + slot] = v;
    }
    if (tid < 48) {
      int row = tid >> 3;
      int cl = ((tid >> 2) & 1) ? 65 : 0;
      int ch = tid & 3;
      int sb = row * 33 + (cl >> 1);
      int slot = (4 * (cl & 1) + ch) ^ (sb & 7);
      inS[sb * 8 + slot] = {0, 0, 0, 0};
    }
    __syncthreads();
#pragma unroll
    for (int tap = 0; tap < 9; tap++) {
      const int dy = tap / 3, dx = tap % 3;
      half8 a[4], bf[4];
#pragma unroll
      for (int mf = 0; mf < 4; mf++) {
        int oc = mf * 16 + l15;
        int sbw = tap * 32 + (oc >> 1);
        a[mf] = ((const half8*)wS)[sbw * 8 + ((4 * (oc & 1) + l4) ^ (sbw & 7))];
      }
#pragma unroll
      for (int nf = 0; nf < 4; nf++) {
        int cl = nf * 16 + l15 + dx;
        int row = w + dy;
        int sb = row * 33 + (cl >> 1);
        bf[nf] = ((const half8*)inS)[sb * 8 + ((4 * (cl & 1) + l4) ^ (sb & 7))];
      }
#pragma unroll
      for (int mf = 0; mf < 4; mf++)
#pragma unroll
        for (int nf = 0; nf < 4; nf++)
          acc[mf][nf] = __builtin_amdgcn_mfma_f32_16x16x32_f16(a[mf], bf[nf], acc[mf][nf], 0, 0, 0);
    }
  }
  const int p_base = (y0 + w) * 64;
#pragma unroll
  for (int mf = 0; mf < 4; mf++) {
    const int ocb = o0 + mf * 16 + l4 * 4;
    const f32x4 bv = *(const f32x4*)(bias + ocb);
#pragma unroll
    for (int nf = 0; nf < 4; nf++) {
      const int p = p_base + nf * 16 + l15;
      if (mode == 0) {
        unsigned short h[4];
#pragma unroll
        for (int r = 0; r < 4; r++)
          h[r] = f2h(fmaxf(acc[mf][nf][r] + bv[r], 0.0f));
        unsigned long long pk = (unsigned long long)h[0] |
                                ((unsigned long long)h[1] << 16) |
                                ((unsigned long long)h[2] << 32) |
                                ((unsigned long long)h[3] << 48);
        *(unsigned long long*)(outT + ((size_t)b * 4096 + p) * 256 + ocb) = pk;
      } else {
#pragma unroll
        for (int r = 0; r < 4; r++)
          outN[((size_t)(b * 256 + ocb + r)) * HW + p] = acc[mf][nf][r] + bv[r];
      }
    }
  }
}

// ---------------- attention pass 1a: partial row stats over a t-quarter -----
__global__ __launch_bounds__(256, 4) void attn_rowstats_part(
    const unsigned short* __restrict__ kT, const unsigned short* __restrict__ qT,
    float* __restrict__ Mp, float* __restrict__ Zp) {
  __shared__ int4 qs4[64][32];   // 32KB [t][c-granule], swizzled
  const int b  = blockIdx.x;
  const int r0 = blockIdx.y * 64;
  const int q  = blockIdx.z;
  const int tid = threadIdx.x;
  const int w = tid >> 6, l = tid & 63;
  const int l4 = l >> 4, l15 = l & 15;
  const int4* qT4 = (const int4*)qT + (size_t)b * HW * 32;
  const half8* kT8 = (const half8*)kT + ((size_t)b * HW + r0) * 32;
  half8 afr[8];                  // wave w owns rows [w*16, w*16+16)
#pragma unroll
  for (int ks = 0; ks < 8; ks++)
    afr[ks] = kT8[(size_t)(w * 16 + l15) * 32 + ks * 4 + l4];
  float m[4], z[4];
#pragma unroll
  for (int i = 0; i < 4; i++) { m[i] = -1e30f; z[i] = 0.0f; }
  for (int t0 = q * 1024; t0 < q * 1024 + 1024; t0 += 64) {
    __syncthreads();
#pragma unroll
    for (int it = 0; it < 8; it++) {
      int id = tid + it * 256;
      int row = id >> 5, ch = id & 31;
      qs4[row][ch ^ (row & 7)] = qT4[(size_t)(t0 + row) * 32 + ch];
    }
    __syncthreads();
    f32x4 acc[4] = {{0.f,0.f,0.f,0.f},{0.f,0.f,0.f,0.f},
                    {0.f,0.f,0.f,0.f},{0.f,0.f,0.f,0.f}};
#pragma unroll
    for (int ks = 0; ks < 8; ks++) {
#pragma unroll
      for (int nf = 0; nf < 4; nf++) {
        int t = nf * 16 + l15;
        half8 bq = ((const half8*)qs4)[t * 32 + ((ks * 4 + l4) ^ (t & 7))];
        acc[nf] = __builtin_amdgcn_mfma_f32_16x16x32_f16(afr[ks], bq, acc[nf], 0, 0, 0);
      }
    }
#pragma unroll
    for (int nf = 0; nf < 4; nf++)
#pragma unroll
      for (int r = 0; r < 4; r++) {
        float sv = acc[nf][r];
        if (sv > m[r]) { z[r] *= __expf(m[r] - sv); m[r] = sv; }
        z[r] += __expf(sv - m[r]);
      }
  }
#pragma unroll
  for (int r = 0; r < 4; r++) {
    for (int off = 1; off < 16; off <<= 1) {
      float mo = __shfl_xor(m[r], off, 16);
      float zo = __shfl_xor(z[r], off, 16);
      float mn = fmaxf(m[r], mo);
      z[r] = z[r] * __expf(m[r] - mn) + zo * __expf(mo - mn);
      m[r] = mn;
    }
  }
  if (l15 == 0) {
#pragma unroll
    for (int r = 0; r < 4; r++) {
      int rr = r0 + w * 16 + l4 * 4 + r;
      Mp[((size_t)b * HW + rr) * 4 + q] = m[r];
      Zp[((size_t)b * HW + rr) * 4 + q] = z[r];
    }
  }
}

// ---------------- attention pass 1b: merge 4 quarters -----------------------
__global__ __launch_bounds__(256) void reduce_mz(
    const float* __restrict__ Mp, const float* __restrict__ Zp,
    float* __restrict__ Mrow, float* __restrict__ Zrow) {
  int i = blockIdx.x * 256 + threadIdx.x;      // 0 .. 8*4096-1
  float4 mq = *(const float4*)(Mp + (size_t)i * 4);
  float4 zq = *(const float4*)(Zp + (size_t)i * 4);
  float M = fmaxf(fmaxf(mq.x, mq.y), fmaxf(mq.z, mq.w));
  float Z = zq.x * __expf(mq.x - M) + zq.y * __expf(mq.y - M)
          + zq.z * __expf(mq.z - M) + zq.w * __expf(mq.w - M);
  Mrow[i] = M;
  Zrow[i] = 1.0f / Z;
}

// ---------------- attention pass 2: R6 + cross-iter K prefetch --------------
__global__ __launch_bounds__(256, 2) void attn_pass2(
    const unsigned short* __restrict__ kT, const unsigned short* __restrict__ qT,
    const unsigned short* __restrict__ vB, const float* __restrict__ Mrow,
    const float* __restrict__ Zrow, const float* __restrict__ alphap,
    const float* __restrict__ betap, float* __restrict__ out) {
  __shared__ int4 qs4[64][32];      // 32KB Q [t][c-granule], swizzled
  __shared__ int4 ps4[2][64][16];   // 2x16KB P [t][r-granule], swizzled
  const int b  = blockIdx.x;
  const int t0 = blockIdx.y * 64;
  const int tid = threadIdx.x;
  const int w = tid >> 6, l = tid & 63;
  const int l4 = l >> 4, l15 = l & 15;
  const int4*  qT4 = (const int4*)qT + ((size_t)b * HW + t0) * 32;
  const half8* kT8 = (const half8*)kT + (size_t)b * HW * 32;
  const half8* vB8 = (const half8*)vB + (size_t)b * 256 * 512;
  const float* Mb = Mrow + (size_t)b * HW;
  const float* Zb = Zrow + (size_t)b * HW;
#pragma unroll
  for (int it = 0; it < 8; it++) {
    int id = tid + it * 256;
    int row = id >> 5, ch = id & 31;
    qs4[row][ch ^ (row & 7)] = qT4[(size_t)row * 32 + ch];
  }
  f32x4 acc_o[4][4];
#pragma unroll
  for (int i = 0; i < 4; i++)
#pragma unroll
    for (int j = 0; j < 4; j++) acc_o[i][j] = {0.f, 0.f, 0.f, 0.f};

  // K double-buffer registers (statically named sets)
  half8 akA0[8], akA1[8], akB0[8], akB1[8];
#pragma unroll
  for (int g = 0; g < 8; g++) {     // preload iter 0 into A
    akA0[g] = kT8[(size_t)(w * 32 + l15) * 32 + g * 4 + l4];
    akA1[g] = kT8[(size_t)(w * 32 + 16 + l15) * 32 + g * 4 + l4];
  }
  __syncthreads();

  // one iteration body: consumes cur K regs, prefetches next into nxt
  auto body = [&](int iter, half8* cur0, half8* cur1, half8* nxt0, half8* nxt1) {
    const int r0 = iter * 128;
    int4* psb = &ps4[iter & 1][0][0];
    // ---- prefetch next iter's K rows (in flight across whole body)
    if (iter < 31) {
      const int rn = r0 + 128;
#pragma unroll
      for (int g = 0; g < 8; g++) {
        nxt0[g] = kT8[(size_t)(rn + w * 32 + l15) * 32 + g * 4 + l4];
        nxt1[g] = kT8[(size_t)(rn + w * 32 + 16 + l15) * 32 + g * 4 + l4];
      }
    }
    // ---- S phase: S[128r][64t], K already resident in regs
    f32x4 acc_s[2][4];
#pragma unroll
    for (int i = 0; i < 2; i++)
#pragma unroll
      for (int j = 0; j < 4; j++) acc_s[i][j] = {0.f, 0.f, 0.f, 0.f};
#pragma unroll
    for (int g = 0; g < 8; g++) {
      half8 bq[4];
#pragma unroll
      for (int nf = 0; nf < 4; nf++) {
        int t = nf * 16 + l15;
        bq[nf] = ((const half8*)qs4)[t * 32 + ((g * 4 + l4) ^ (t & 7))];
      }
#pragma unroll
      for (int nf = 0; nf < 4; nf++) {
        acc_s[0][nf] = __builtin_amdgcn_mfma_f32_16x16x32_f16(cur0[g], bq[nf], acc_s[0][nf], 0, 0, 0);
        acc_s[1][nf] = __builtin_amdgcn_mfma_f32_16x16x32_f16(cur1[g], bq[nf], acc_s[1][nf], 0, 0, 0);
      }
    }
    // ---- V preload, first half (cc4 0,1)
    half8 avr[4][4];   // [cc4][ks]
#pragma unroll
    for (int cc4 = 0; cc4 < 2; cc4++) {
      const int c = cc4 * 64 + w * 16 + l15;
#pragma unroll
      for (int ks = 0; ks < 4; ks++)
        avr[cc4][ks] = vB8[(size_t)c * 512 + (r0 >> 3) + ks * 4 + l4];
    }
    // ---- P = exp(S - M_r) * rZ_r -> psb[t][r] packed fp16
#pragma unroll
    for (int mfl = 0; mfl < 2; mfl++) {
      int rbase = r0 + w * 32 + mfl * 16 + l4 * 4;
      f32x4 Mv = *(const f32x4*)(Mb + rbase);
      f32x4 Zv = *(const f32x4*)(Zb + rbase);
      int slot = w * 8 + mfl * 4 + l4;
#pragma unroll
      for (int nf = 0; nf < 4; nf++) {
        int t = nf * 16 + l15;
        unsigned lo = (unsigned)f2h(__expf(acc_s[mfl][nf][0] - Mv[0]) * Zv[0])
                    | ((unsigned)f2h(__expf(acc_s[mfl][nf][1] - Mv[1]) * Zv[1]) << 16);
        unsigned hi = (unsigned)f2h(__expf(acc_s[mfl][nf][2] - Mv[2]) * Zv[2])
                    | ((unsigned)f2h(__expf(acc_s[mfl][nf][3] - Mv[3]) * Zv[3]) << 16);
        int ch = slot >> 1;
        int fslot = ((ch ^ (t & 7)) << 1) | (slot & 1);
        ((unsigned long long*)psb)[(size_t)t * 32 + fslot] =
            ((unsigned long long)hi << 32) | (unsigned long long)lo;
      }
    }
    __syncthreads();   // P visible; prev-iter PV reads (other buffer) done
    // ---- V preload, second half (cc4 2,3)
#pragma unroll
    for (int cc4 = 2; cc4 < 4; cc4++) {
      const int c = cc4 * 64 + w * 16 + l15;
#pragma unroll
      for (int ks = 0; ks < 4; ks++)
        avr[cc4][ks] = vB8[(size_t)c * 512 + (r0 >> 3) + ks * 4 + l4];
    }
    // ---- PV: each P fragment LDS-read once, V from regs
#pragma unroll
    for (int ks = 0; ks < 4; ks++) {
#pragma unroll
      for (int nf = 0; nf < 4; nf++) {
        int t = nf * 16 + l15;
        half8 bp = ((const half8*)psb)[t * 16 + ((ks * 4 + l4) ^ (t & 7))];
#pragma unroll
        for (int cc4 = 0; cc4 < 4; cc4++)
          acc_o[cc4][nf] = __builtin_amdgcn_mfma_f32_16x16x32_f16(avr[cc4][ks], bp, acc_o[cc4][nf], 0, 0, 0);
      }
    }
  };

#pragma unroll 1
  for (int it2 = 0; it2 < 16; it2++) {
    body(2 * it2,     akA0, akA1, akB0, akB1);
    body(2 * it2 + 1, akB0, akB1, akA0, akA1);
  }

  // ---- epilogue: out = alpha*cb + beta*attn (cb already in out)
  const float alpha = alphap[0], beta = betap[0];
#pragma unroll
  for (int cc4 = 0; cc4 < 4; cc4++) {
    int cbase = cc4 * 64 + w * 16 + l4 * 4;
#pragma unroll
    for (int nf = 0; nf < 4; nf++) {
      int t = t0 + nf * 16 + l15;
#pragma unroll
      for (int r = 0; r < 4; r++) {
        size_t idx = ((size_t)(b * 256 + cbase + r)) * HW + t;
        out[idx] = alpha * out[idx] + beta * acc_o[cc4][nf][r];
      }
    }
  }
}

extern "C" void kernel_launch(void* const* d_in, const int* in_sizes, int n_in,
                              void* d_out, int out_size, void* d_ws, size_t ws_size,
                              hipStream_t stream) {
  (void)in_sizes; (void)n_in; (void)out_size; (void)ws_size;
  const float* x   = (const float*)d_in[0];
  const float* w1  = (const float*)d_in[1];
  const float* b1  = (const float*)d_in[2];
  const float* w2  = (const float*)d_in[3];
  const float* b2  = (const float*)d_in[4];
  const float* w3  = (const float*)d_in[5];
  const float* b3  = (const float*)d_in[6];
  const float* wb1 = (const float*)d_in[7];
  const float* bb1 = (const float*)d_in[8];
  const float* wb2 = (const float*)d_in[9];
  const float* bb2 = (const float*)d_in[10];
  const float* wq  = (const float*)d_in[11];
  const float* bq  = (const float*)d_in[12];
  const float* wk  = (const float*)d_in[13];
  const float* bk  = (const float*)d_in[14];
  const float* wv  = (const float*)d_in[15];
  const float* bv  = (const float*)d_in[16];
  const float* alpha = (const float*)d_in[17];
  const float* beta  = (const float*)d_in[18];
  float* out = (float*)d_out;

  const size_t SZH = (size_t)NB * 4096 * 256;   // 8,388,608 halves = 16MB
  unsigned short* wsh = (unsigned short*)d_ws;
  unsigned short* xh  = wsh;
  unsigned short* xfT = wsh + SZH;
  unsigned short* qT  = wsh + 2 * SZH;
  unsigned short* kT  = wsh + 3 * SZH;
  unsigned short* vN  = wsh + 4 * SZH;
  unsigned short* y1T = wsh + 5 * SZH;
  unsigned short* y2T = y1T + SZH / 4;
  unsigned short* t1T = wsh + 5 * SZH;
  float* Mrow = (float*)(wsh + 6 * SZH);
  float* Zrow = Mrow + (size_t)NB * HW;
  float* Mp   = Zrow + (size_t)NB * HW;         // [B*HW*4] partials
  float* Zp   = Mp + (size_t)NB * HW * 4;
  unsigned short* wh   = (unsigned short*)(Zp + (size_t)NB * HW * 4);
  unsigned short* w1h  = wh;
  unsigned short* w2h  = wh + 16384;
  unsigned short* w3h  = wh + 24576;
  unsigned short* wqh  = wh + 57344;
  unsigned short* wkh  = wh + 122880;
  unsigned short* wvh  = wh + 188416;
  unsigned short* wA1h = wh + 253952;
  unsigned short* wA2h = wA1h + (size_t)256 * 9 * 256;

  wcvt6<<<992, 256, 0, stream>>>(w1, w2, w3, wq, wk, wv, wh);
  wreorder<<<256, 256, 0, stream>>>(wb1, wA1h);
  wreorder<<<256, 256, 0, stream>>>(wb2, wA2h);
  transpose_cvt_h<<<dim3(8, 64, 4), 256, 0, stream>>>(x, xh);
  gemm1x1_h<<<dim3(8, 16, 1), 256, 0, stream>>>(w1h, b1, xh,  y1T, nullptr, 256,  64, 0, 1);
  gemm1x1_h<<<dim3(8, 16, 2), 256, 0, stream>>>(w2h, b2, y1T, y2T, nullptr,  64, 128, 0, 1);
  gemm1x1_h<<<dim3(8, 16, 4), 256, 0, stream>>>(w3h, b3, y2T, xfT, nullptr, 128, 256, 0, 1);
  gemm1x1_h<<<dim3(8, 16, 4), 256, 0, stream>>>(wqh, bq, xfT, qT,  nullptr, 256, 256, 0, 0);
  gemm1x1_h<<<dim3(8, 16, 4), 256, 0, stream>>>(wkh, bk, xfT, kT,  nullptr, 256, 256, 0, 0);
  gemm1x1_h<<<dim3(8, 16, 4), 256, 0, stream>>>(wvh, bv, xfT, nullptr, vN,  256, 256, 1, 0);
  conv3x3_mfma<<<dim3(8, 16, 4), 256, 0, stream>>>(xfT, wA1h, bb1, t1T, nullptr, 0);
  conv3x3_mfma<<<dim3(8, 16, 4), 256, 0, stream>>>(t1T, wA2h, bb2, nullptr, out, 1);
  attn_rowstats_part<<<dim3(8, 64, 4), 256, 0, stream>>>(kT, qT, Mp, Zp);
  reduce_mz<<<128, 256, 0, stream>>>(Mp, Zp, Mrow, Zrow);
  attn_pass2<<<dim3(8, 64), 256, 0, stream>>>(kT, qT, vN, Mrow, Zrow,
                                              alpha, beta, out);
}

// Round 10
// 553.741 us; speedup vs baseline: 1.3835x; 1.0555x over previous
//
#include <hip/hip_runtime.h>
#include <cstdint>

// AttCM R9: pass2 = R6 + HALF-K cross-iter prefetch via token-pasted macro
// (static register names — R8's lambda-pointer version forced K to scratch:
// WRITE_SIZE 33->176MB) + s_setprio(1) around MFMA clusters (T5).
// Full K-dbuf needs ~264 VGPR (spills); half fits (~230 peak).
// Shapes: B=8, C=256, HW=4096.

#define HW 4096
#define NB 8

typedef __attribute__((ext_vector_type(8))) _Float16 half8;    // 8 fp16 = 4 VGPR
typedef __attribute__((ext_vector_type(4))) float f32x4;       // MFMA C/D

static __device__ __forceinline__ unsigned short f2h(float x) {
  _Float16 h = (_Float16)x;
  return __builtin_bit_cast(unsigned short, h);
}

// ---------------- 1x1 weights fp32 -> fp16, all six packed ----------------
__global__ __launch_bounds__(256) void wcvt6(
    const float* __restrict__ w1, const float* __restrict__ w2,
    const float* __restrict__ w3, const float* __restrict__ wq,
    const float* __restrict__ wk, const float* __restrict__ wv,
    unsigned short* __restrict__ dst) {
  int i = blockIdx.x * 256 + threadIdx.x;
  const float* src; int off;
  if      (i <  16384) { src = w1; off = 0; }
  else if (i <  24576) { src = w2; off = 16384; }
  else if (i <  57344) { src = w3; off = 24576; }
  else if (i < 122880) { src = wq; off = 57344; }
  else if (i < 188416) { src = wk; off = 122880; }
  else                 { src = wv; off = 188416; }
  dst[i] = f2h(src[i - off]);
}

// ---------------- conv weight reorder: OIHW fp32 -> [o][tap][c] fp16 --------
__global__ __launch_bounds__(256) void wreorder(
    const float* __restrict__ w, unsigned short* __restrict__ wA) {
  const int o = blockIdx.x;
  const int c = threadIdx.x;
  const float* wp = w + ((size_t)o * 256 + c) * 9;
#pragma unroll
  for (int tap = 0; tap < 9; tap++)
    wA[((size_t)o * 9 + tap) * 256 + c] = f2h(wp[tap]);
}

// ---------------- fp32 [b][c][p] -> fp16 transposed [b][p][c] ----------------
__global__ __launch_bounds__(256) void transpose_cvt_h(
    const float* __restrict__ in, unsigned short* __restrict__ outT) {
  __shared__ float Ts[64][65];
  const int b  = blockIdx.x;
  const int t0 = blockIdx.y * 64;
  const int c0 = blockIdx.z * 64;
  const int tid = threadIdx.x;
#pragma unroll
  for (int it = 0; it < 4; it++) {
    int id = tid + it * 256;
    int c = id >> 4, f4 = id & 15;
    float4 v = *(const float4*)(in + ((size_t)(b * 256 + c0 + c)) * HW + t0 + f4 * 4);
    Ts[c][f4 * 4 + 0] = v.x; Ts[c][f4 * 4 + 1] = v.y;
    Ts[c][f4 * 4 + 2] = v.z; Ts[c][f4 * 4 + 3] = v.w;
  }
  __syncthreads();
#pragma unroll
  for (int it = 0; it < 2; it++) {
    int id = tid + it * 256;
    int t = id >> 3, ch = id & 7;
    unsigned short h[8];
#pragma unroll
    for (int e = 0; e < 8; e++) h[e] = f2h(Ts[ch * 8 + e][t]);
    int4 pk;
    pk.x = (int)((unsigned)h[0] | ((unsigned)h[1] << 16));
    pk.y = (int)((unsigned)h[2] | ((unsigned)h[3] << 16));
    pk.z = (int)((unsigned)h[4] | ((unsigned)h[5] << 16));
    pk.w = (int)((unsigned)h[6] | ((unsigned)h[7] << 16));
    ((int4*)outT)[((size_t)b * HW + t0 + t) * 32 + (c0 >> 3) + ch] = pk;
  }
}

// ---------------- 1x1 conv: fp16 MFMA GEMM, fused layout epilogue ----------
__global__ __launch_bounds__(256) void gemm1x1_h(
    const unsigned short* __restrict__ Wh,   // fp16 [M][K]
    const float* __restrict__ bias,
    const unsigned short* __restrict__ Xt,   // fp16 [b][4096][K]
    unsigned short* __restrict__ outT,
    unsigned short* __restrict__ outN,
    int K, int M, int mode, int doRelu) {
  __shared__ int4 WsL[64 * 32];
  __shared__ int4 XsL[128 * 8];
  const int b  = blockIdx.x;
  const int p0 = blockIdx.y * 256;
  const int m0 = blockIdx.z * 64;
  const int tid = threadIdx.x;
  const int w = tid >> 6, l = tid & 63;
  const int l4 = l >> 4, l15 = l & 15;
  const int KG  = K >> 3;
  const int kgl = (K >= 256) ? 5 : (K >= 128) ? 4 : 3;
  const int4* Wh4 = (const int4*)Wh;
  const int4* Xt4 = (const int4*)Xt + (size_t)(b * 4096 + p0) * KG;
  for (int id = tid; id < 64 * KG; id += 256) {
    int row = id >> kgl, g = id & (KG - 1);
    WsL[row * KG + (g ^ (row & 7))] = Wh4[(size_t)(m0 + row) * KG + g];
  }
  f32x4 acc[4][4];
#pragma unroll
  for (int i = 0; i < 4; i++)
#pragma unroll
    for (int j = 0; j < 4; j++) acc[i][j] = {0.f, 0.f, 0.f, 0.f};
  const int NCC = K >> 5;
  for (int cc = 0; cc < NCC; cc++) {
    __syncthreads();
#pragma unroll
    for (int it = 0; it < 4; it++) {
      int id = tid + it * 256;
      int p = id >> 2, ch = id & 3;
      XsL[(p >> 1) * 8 + ((((p & 1) << 2) + ch) ^ ((p >> 1) & 7))] =
          Xt4[(size_t)p * KG + cc * 4 + ch];
    }
    __syncthreads();
    half8 a[4], bx[4];
#pragma unroll
    for (int mf = 0; mf < 4; mf++) {
      int m = mf * 16 + l15;
      a[mf] = ((const half8*)WsL)[m * KG + ((cc * 4 + l4) ^ (m & 7))];
    }
#pragma unroll
    for (int nf = 0; nf < 4; nf++) {
      int p = w * 64 + nf * 16 + l15;
      bx[nf] = ((const half8*)XsL)[(p >> 1) * 8 + ((((p & 1) << 2) + l4) ^ ((p >> 1) & 7))];
    }
#pragma unroll
    for (int mf = 0; mf < 4; mf++)
#pragma unroll
      for (int nf = 0; nf < 4; nf++)
        acc[mf][nf] = __builtin_amdgcn_mfma_f32_16x16x32_f16(a[mf], bx[nf], acc[mf][nf], 0, 0, 0);
  }
#pragma unroll
  for (int mf = 0; mf < 4; mf++) {
    const int mrow = m0 + mf * 16 + l4 * 4;
    const f32x4 bv = *(const f32x4*)(bias + mrow);
#pragma unroll
    for (int nf = 0; nf < 4; nf++) {
      const int p = p0 + w * 64 + nf * 16 + l15;
      float vr[4];
#pragma unroll
      for (int r = 0; r < 4; r++) {
        float v = acc[mf][nf][r] + bv[r];
        if (doRelu) v = fmaxf(v, 0.0f);
        vr[r] = v;
      }
      if (mode == 0) {
        unsigned long long pk = (unsigned long long)f2h(vr[0]) |
                                ((unsigned long long)f2h(vr[1]) << 16) |
                                ((unsigned long long)f2h(vr[2]) << 32) |
                                ((unsigned long long)f2h(vr[3]) << 48);
        *(unsigned long long*)(outT + ((size_t)b * 4096 + p) * M + mrow) = pk;
      } else {
#pragma unroll
        for (int r = 0; r < 4; r++)
          outN[((size_t)(b * M + mrow + r)) * 4096 + p] = f2h(vr[r]);
      }
    }
  }
}

// ---------------- 3x3 conv, fp16 MFMA implicit GEMM (unchanged) ------------
__global__ __launch_bounds__(256, 2) void conv3x3_mfma(
    const unsigned short* __restrict__ inT,
    const unsigned short* __restrict__ wA,
    const float* __restrict__ bias,
    unsigned short* __restrict__ outT,
    float* __restrict__ outN,
    int mode) {
  __shared__ int4 wS[2304];
  __shared__ int4 inS[1584];
  const int b  = blockIdx.x;
  const int y0 = blockIdx.y * 4;
  const int o0 = blockIdx.z * 64;
  const int tid = threadIdx.x;
  const int w = tid >> 6, l = tid & 63;
  const int l4 = l >> 4, l15 = l & 15;
  const int4* inT4 = (const int4*)inT + (size_t)b * 4096 * 32;
  const int4* wA4  = (const int4*)wA;
  f32x4 acc[4][4];
#pragma unroll
  for (int i = 0; i < 4; i++)
#pragma unroll
    for (int j = 0; j < 4; j++) acc[i][j] = {0.f, 0.f, 0.f, 0.f};

  for (int c0 = 0; c0 < 256; c0 += 32) {
    __syncthreads();
#pragma unroll
    for (int it = 0; it < 9; it++) {
      int id = it * 256 + tid;
      int ch = id & 3;
      int r  = id >> 2;
      int tap = r % 9, ol = r / 9;
      int sbw = tap * 32 + (ol >> 1);
      int slot = (4 * (ol & 1) + ch) ^ (sbw & 7);
      wS[sbw * 8 + slot] = wA4[((size_t)(o0 + ol) * 9 + tap) * 32 + (c0 >> 3) + ch];
    }
#pragma unroll
    for (int it = 0; it < 6; it++) {
      int ch = tid & 3;
      int col = tid >> 2;
      int yimg = y0 + it - 1;
      int4 v = {0, 0, 0, 0};
      if (yimg >= 0 && yimg < 64)
        v = inT4[(size_t)(yimg * 64 + col) * 32 + (c0 >> 3) + ch];
      int cl = col + 1;
      int sb = it * 33 + (cl >> 1);
      int slot = (4 * (cl & 1) + ch) ^ (sb & 7);
      inS[sb * 8 + slot] = v;
    }
    if (tid < 48) {
      int row = tid >> 3;
      int cl = ((tid >> 2) & 1) ? 65 : 0;
      int ch = tid & 3;
      int sb = row * 33 + (cl >> 1);
      int slot = (4 * (cl & 1) + ch) ^ (sb & 7);
      inS[sb * 8 + slot] = {0, 0, 0, 0};
    }
    __syncthreads();
#pragma unroll
    for (int tap = 0; tap < 9; tap++) {
      const int dy = tap / 3, dx = tap % 3;
      half8 a[4], bf[4];
#pragma unroll
      for (int mf = 0; mf < 4; mf++) {
        int oc = mf * 16 + l15;
        int sbw = tap * 32 + (oc >> 1);
        a[mf] = ((const half8*)wS)[sbw * 8 + ((4 * (oc & 1) + l4) ^ (sbw & 7))];
      }
#pragma unroll
      for (int nf = 0; nf < 4; nf++) {
        int cl = nf * 16 + l15 + dx;
        int row = w + dy;
        int sb = row * 33 + (cl >> 1);
        bf[nf] = ((const half8*)inS)[sb * 8 + ((4 * (cl & 1) + l4) ^ (sb & 7))];
      }
#pragma unroll
      for (int mf = 0; mf < 4; mf++)
#pragma unroll
        for (int nf = 0; nf < 4; nf++)
          acc[mf][nf] = __builtin_amdgcn_mfma_f32_16x16x32_f16(a[mf], bf[nf], acc[mf][nf], 0, 0, 0);
    }
  }
  const int p_base = (y0 + w) * 64;
#pragma unroll
  for (int mf = 0; mf < 4; mf++) {
    const int ocb = o0 + mf * 16 + l4 * 4;
    const f32x4 bv = *(const f32x4*)(bias + ocb);
#pragma unroll
    for (int nf = 0; nf < 4; nf++) {
      const int p = p_base + nf * 16 + l15;
      if (mode == 0) {
        unsigned short h[4];
#pragma unroll
        for (int r = 0; r < 4; r++)
          h[r] = f2h(fmaxf(acc[mf][nf][r] + bv[r], 0.0f));
        unsigned long long pk = (unsigned long long)h[0] |
                                ((unsigned long long)h[1] << 16) |
                                ((unsigned long long)h[2] << 32) |
                                ((unsigned long long)h[3] << 48);
        *(unsigned long long*)(outT + ((size_t)b * 4096 + p) * 256 + ocb) = pk;
      } else {
#pragma unroll
        for (int r = 0; r < 4; r++)
          outN[((size_t)(b * 256 + ocb + r)) * HW + p] = acc[mf][nf][r] + bv[r];
      }
    }
  }
}

// ---------------- attention pass 1a: partial row stats over a t-quarter -----
__global__ __launch_bounds__(256, 4) void attn_rowstats_part(
    const unsigned short* __restrict__ kT, const unsigned short* __restrict__ qT,
    float* __restrict__ Mp, float* __restrict__ Zp) {
  __shared__ int4 qs4[64][32];   // 32KB [t][c-granule], swizzled
  const int b  = blockIdx.x;
  const int r0 = blockIdx.y * 64;
  const int q  = blockIdx.z;
  const int tid = threadIdx.x;
  const int w = tid >> 6, l = tid & 63;
  const int l4 = l >> 4, l15 = l & 15;
  const int4* qT4 = (const int4*)qT + (size_t)b * HW * 32;
  const half8* kT8 = (const half8*)kT + ((size_t)b * HW + r0) * 32;
  half8 afr[8];                  // wave w owns rows [w*16, w*16+16)
#pragma unroll
  for (int ks = 0; ks < 8; ks++)
    afr[ks] = kT8[(size_t)(w * 16 + l15) * 32 + ks * 4 + l4];
  float m[4], z[4];
#pragma unroll
  for (int i = 0; i < 4; i++) { m[i] = -1e30f; z[i] = 0.0f; }
  for (int t0 = q * 1024; t0 < q * 1024 + 1024; t0 += 64) {
    __syncthreads();
#pragma unroll
    for (int it = 0; it < 8; it++) {
      int id = tid + it * 256;
      int row = id >> 5, ch = id & 31;
      qs4[row][ch ^ (row & 7)] = qT4[(size_t)(t0 + row) * 32 + ch];
    }
    __syncthreads();
    f32x4 acc[4] = {{0.f,0.f,0.f,0.f},{0.f,0.f,0.f,0.f},
                    {0.f,0.f,0.f,0.f},{0.f,0.f,0.f,0.f}};
#pragma unroll
    for (int ks = 0; ks < 8; ks++) {
#pragma unroll
      for (int nf = 0; nf < 4; nf++) {
        int t = nf * 16 + l15;
        half8 bq = ((const half8*)qs4)[t * 32 + ((ks * 4 + l4) ^ (t & 7))];
        acc[nf] = __builtin_amdgcn_mfma_f32_16x16x32_f16(afr[ks], bq, acc[nf], 0, 0, 0);
      }
    }
#pragma unroll
    for (int nf = 0; nf < 4; nf++)
#pragma unroll
      for (int r = 0; r < 4; r++) {
        float sv = acc[nf][r];
        if (sv > m[r]) { z[r] *= __expf(m[r] - sv); m[r] = sv; }
        z[r] += __expf(sv - m[r]);
      }
  }
#pragma unroll
  for (int r = 0; r < 4; r++) {
    for (int off = 1; off < 16; off <<= 1) {
      float mo = __shfl_xor(m[r], off, 16);
      float zo = __shfl_xor(z[r], off, 16);
      float mn = fmaxf(m[r], mo);
      z[r] = z[r] * __expf(m[r] - mn) + zo * __expf(mo - mn);
      m[r] = mn;
    }
  }
  if (l15 == 0) {
#pragma unroll
    for (int r = 0; r < 4; r++) {
      int rr = r0 + w * 16 + l4 * 4 + r;
      Mp[((size_t)b * HW + rr) * 4 + q] = m[r];
      Zp[((size_t)b * HW + rr) * 4 + q] = z[r];
    }
  }
}

// ---------------- attention pass 1b: merge 4 quarters -----------------------
__global__ __launch_bounds__(256) void reduce_mz(
    const float* __restrict__ Mp, const float* __restrict__ Zp,
    float* __restrict__ Mrow, float* __restrict__ Zrow) {
  int i = blockIdx.x * 256 + threadIdx.x;      // 0 .. 8*4096-1
  float4 mq = *(const float4*)(Mp + (size_t)i * 4);
  float4 zq = *(const float4*)(Zp + (size_t)i * 4);
  float M = fmaxf(fmaxf(mq.x, mq.y), fmaxf(mq.z, mq.w));
  float Z = zq.x * __expf(mq.x - M) + zq.y * __expf(mq.y - M)
          + zq.z * __expf(mq.z - M) + zq.w * __expf(mq.w - M);
  Mrow[i] = M;
  Zrow[i] = 1.0f / Z;
}

// ---------------- attention pass 2: R6 + half-K prefetch (static) + setprio -
// One iteration, expanded via macro so every register array index is static.
// CURP = prefetched K rows for mfl=0 (ready); akL loaded fresh for mfl=1 and
// covered by CURP's MFMAs; NXTP = prefetch of next iter's mfl=0 rows.
#define P2_ITER(ITER, CURP, NXTP)                                              \
  {                                                                            \
    const int r0 = (ITER) * 128;                                               \
    int4* psb = &ps4[(ITER) & 1][0][0];                                        \
    _Pragma("unroll")                                                          \
    for (int g = 0; g < 8; g++)                                                \
      akL[g] = kT8[(size_t)(r0 + w * 32 + 16 + l15) * 32 + g * 4 + l4];        \
    if ((ITER) < 31) {                                                         \
      _Pragma("unroll")                                                        \
      for (int g = 0; g < 8; g++)                                              \
        NXTP[g] = kT8[(size_t)(r0 + 128 + w * 32 + l15) * 32 + g * 4 + l4];    \
    }                                                                          \
    f32x4 acc_s[2][4];                                                         \
    _Pragma("unroll")                                                          \
    for (int i = 0; i < 2; i++)                                                \
      _Pragma("unroll")                                                        \
      for (int j = 0; j < 4; j++) acc_s[i][j] = {0.f, 0.f, 0.f, 0.f};          \
    __builtin_amdgcn_s_setprio(1);                                             \
    _Pragma("unroll")                                                          \
    for (int g = 0; g < 8; g++) {                                              \
      half8 bq[4];                                                             \
      _Pragma("unroll")                                                        \
      for (int nf = 0; nf < 4; nf++) {                                         \
        int t = nf * 16 + l15;                                                 \
        bq[nf] = ((const half8*)qs4)[t * 32 + ((g * 4 + l4) ^ (t & 7))];       \
      }                                                                        \
      _Pragma("unroll")                                                        \
      for (int nf = 0; nf < 4; nf++)                                           \
        acc_s[0][nf] = __builtin_amdgcn_mfma_f32_16x16x32_f16(CURP[g], bq[nf], acc_s[0][nf], 0, 0, 0); \
      _Pragma("unroll")                                                        \
      for (int nf = 0; nf < 4; nf++)                                           \
        acc_s[1][nf] = __builtin_amdgcn_mfma_f32_16x16x32_f16(akL[g], bq[nf], acc_s[1][nf], 0, 0, 0);  \
    }                                                                          \
    __builtin_amdgcn_s_setprio(0);                                             \
    half8 avr[4][4];                                                           \
    _Pragma("unroll")                                                          \
    for (int cc4 = 0; cc4 < 2; cc4++) {                                        \
      const int c = cc4 * 64 + w * 16 + l15;                                   \
      _Pragma("unroll")                                                        \
      for (int ks = 0; ks < 4; ks++)                                           \
        avr[cc4][ks] = vB8[(size_t)c * 512 + (r0 >> 3) + ks * 4 + l4];         \
    }                                                                          \
    _Pragma("unroll")                                                          \
    for (int mfl = 0; mfl < 2; mfl++) {                                        \
      int rbase = r0 + w * 32 + mfl * 16 + l4 * 4;                             \
      f32x4 Mv = *(const f32x4*)(Mb + rbase);                                  \
      f32x4 Zv = *(const f32x4*)(Zb + rbase);                                  \
      int slot = w * 8 + mfl * 4 + l4;                                         \
      _Pragma("unroll")                                                        \
      for (int nf = 0; nf < 4; nf++) {                                         \
        int t = nf * 16 + l15;                                                 \
        unsigned lo = (unsigned)f2h(__expf(acc_s[mfl][nf][0] - Mv[0]) * Zv[0]) \
                    | ((unsigned)f2h(__expf(acc_s[mfl][nf][1] - Mv[1]) * Zv[1]) << 16); \
        unsigned hi = (unsigned)f2h(__expf(acc_s[mfl][nf][2] - Mv[2]) * Zv[2]) \
                    | ((unsigned)f2h(__expf(acc_s[mfl][nf][3] - Mv[3]) * Zv[3]) << 16); \
        int ch = slot >> 1;                                                    \
        int fslot = ((ch ^ (t & 7)) << 1) | (slot & 1);                        \
        ((unsigned long long*)psb)[(size_t)t * 32 + fslot] =                   \
            ((unsigned long long)hi << 32) | (unsigned long long)lo;           \
      }                                                                        \
    }                                                                          \
    __syncthreads();                                                           \
    _Pragma("unroll")                                                          \
    for (int cc4 = 2; cc4 < 4; cc4++) {                                        \
      const int c = cc4 * 64 + w * 16 + l15;                                   \
      _Pragma("unroll")                                                        \
      for (int ks = 0; ks < 4; ks++)                                           \
        avr[cc4][ks] = vB8[(size_t)c * 512 + (r0 >> 3) + ks * 4 + l4];         \
    }                                                                          \
    __builtin_amdgcn_s_setprio(1);                                             \
    _Pragma("unroll")                                                          \
    for (int ks = 0; ks < 4; ks++) {                                           \
      _Pragma("unroll")                                                        \
      for (int nf = 0; nf < 4; nf++) {                                         \
        int t = nf * 16 + l15;                                                 \
        half8 bp = ((const half8*)psb)[t * 16 + ((ks * 4 + l4) ^ (t & 7))];    \
        _Pragma("unroll")                                                      \
        for (int cc4 = 0; cc4 < 4; cc4++)                                      \
          acc_o[cc4][nf] = __builtin_amdgcn_mfma_f32_16x16x32_f16(avr[cc4][ks], bp, acc_o[cc4][nf], 0, 0, 0); \
      }                                                                        \
    }                                                                          \
    __builtin_amdgcn_s_setprio(0);                                             \
  }

__global__ __launch_bounds__(256, 2) void attn_pass2(
    const unsigned short* __restrict__ kT, const unsigned short* __restrict__ qT,
    const unsigned short* __restrict__ vB, const float* __restrict__ Mrow,
    const float* __restrict__ Zrow, const float* __restrict__ alphap,
    const float* __restrict__ betap, float* __restrict__ out) {
  __shared__ int4 qs4[64][32];      // 32KB Q [t][c-granule], swizzled
  __shared__ int4 ps4[2][64][16];   // 2x16KB P [t][r-granule], swizzled
  const int b  = blockIdx.x;
  const int t0 = blockIdx.y * 64;
  const int tid = threadIdx.x;
  const int w = tid >> 6, l = tid & 63;
  const int l4 = l >> 4, l15 = l & 15;
  const int4*  qT4 = (const int4*)qT + ((size_t)b * HW + t0) * 32;
  const half8* kT8 = (const half8*)kT + (size_t)b * HW * 32;
  const half8* vB8 = (const half8*)vB + (size_t)b * 256 * 512;
  const float* Mb = Mrow + (size_t)b * HW;
  const float* Zb = Zrow + (size_t)b * HW;
#pragma unroll
  for (int it = 0; it < 8; it++) {
    int id = tid + it * 256;
    int row = id >> 5, ch = id & 31;
    qs4[row][ch ^ (row & 7)] = qT4[(size_t)row * 32 + ch];
  }
  f32x4 acc_o[4][4];
#pragma unroll
  for (int i = 0; i < 4; i++)
#pragma unroll
    for (int j = 0; j < 4; j++) acc_o[i][j] = {0.f, 0.f, 0.f, 0.f};

  half8 akA[8], akB[8], akL[8];     // static-named: prefetch ping-pong + local
#pragma unroll
  for (int g = 0; g < 8; g++)       // preload iter 0 mfl=0 rows
    akA[g] = kT8[(size_t)(w * 32 + l15) * 32 + g * 4 + l4];
  __syncthreads();                  // Q staged

#pragma unroll 1
  for (int it2 = 0; it2 < 16; it2++) {
    P2_ITER(2 * it2,     akA, akB)
    P2_ITER(2 * it2 + 1, akB, akA)
  }

  // ---- epilogue: out = alpha*cb + beta*attn (cb already in out)
  const float alpha = alphap[0], beta = betap[0];
#pragma unroll
  for (int cc4 = 0; cc4 < 4; cc4++) {
    int cbase = cc4 * 64 + w * 16 + l4 * 4;
#pragma unroll
    for (int nf = 0; nf < 4; nf++) {
      int t = t0 + nf * 16 + l15;
#pragma unroll
      for (int r = 0; r < 4; r++) {
        size_t idx = ((size_t)(b * 256 + cbase + r)) * HW + t;
        out[idx] = alpha * out[idx] + beta * acc_o[cc4][nf][r];
      }
    }
  }
}

extern "C" void kernel_launch(void* const* d_in, const int* in_sizes, int n_in,
                              void* d_out, int out_size, void* d_ws, size_t ws_size,
                              hipStream_t stream) {
  (void)in_sizes; (void)n_in; (void)out_size; (void)ws_size;
  const float* x   = (const float*)d_in[0];
  const float* w1  = (const float*)d_in[1];
  const float* b1  = (const float*)d_in[2];
  const float* w2  = (const float*)d_in[3];
  const float* b2  = (const float*)d_in[4];
  const float* w3  = (const float*)d_in[5];
  const float* b3  = (const float*)d_in[6];
  const float* wb1 = (const float*)d_in[7];
  const float* bb1 = (const float*)d_in[8];
  const float* wb2 = (const float*)d_in[9];
  const float* bb2 = (const float*)d_in[10];
  const float* wq  = (const float*)d_in[11];
  const float* bq  = (const float*)d_in[12];
  const float* wk  = (const float*)d_in[13];
  const float* bk  = (const float*)d_in[14];
  const float* wv  = (const float*)d_in[15];
  const float* bv  = (const float*)d_in[16];
  const float* alpha = (const float*)d_in[17];
  const float* beta  = (const float*)d_in[18];
  float* out = (float*)d_out;

  const size_t SZH = (size_t)NB * 4096 * 256;   // 8,388,608 halves = 16MB
  unsigned short* wsh = (unsigned short*)d_ws;
  unsigned short* xh  = wsh;
  unsigned short* xfT = wsh + SZH;
  unsigned short* qT  = wsh + 2 * SZH;
  unsigned short* kT  = wsh + 3 * SZH;
  unsigned short* vN  = wsh + 4 * SZH;
  unsigned short* y1T = wsh + 5 * SZH;
  unsigned short* y2T = y1T + SZH / 4;
  unsigned short* t1T = wsh + 5 * SZH;
  float* Mrow = (float*)(wsh + 6 * SZH);
  float* Zrow = Mrow + (size_t)NB * HW;
  float* Mp   = Zrow + (size_t)NB * HW;         // [B*HW*4] partials
  float* Zp   = Mp + (size_t)NB * HW * 4;
  unsigned short* wh   = (unsigned short*)(Zp + (size_t)NB * HW * 4);
  unsigned short* w1h  = wh;
  unsigned short* w2h  = wh + 16384;
  unsigned short* w3h  = wh + 24576;
  unsigned short* wqh  = wh + 57344;
  unsigned short* wkh  = wh + 122880;
  unsigned short* wvh  = wh + 188416;
  unsigned short* wA1h = wh + 253952;
  unsigned short* wA2h = wA1h + (size_t)256 * 9 * 256;

  wcvt6<<<992, 256, 0, stream>>>(w1, w2, w3, wq, wk, wv, wh);
  wreorder<<<256, 256, 0, stream>>>(wb1, wA1h);
  wreorder<<<256, 256, 0, stream>>>(wb2, wA2h);
  transpose_cvt_h<<<dim3(8, 64, 4), 256, 0, stream>>>(x, xh);
  gemm1x1_h<<<dim3(8, 16, 1), 256, 0, stream>>>(w1h, b1, xh,  y1T, nullptr, 256,  64, 0, 1);
  gemm1x1_h<<<dim3(8, 16, 2), 256, 0, stream>>>(w2h, b2, y1T, y2T, nullptr,  64, 128, 0, 1);
  gemm1x1_h<<<dim3(8, 16, 4), 256, 0, stream>>>(w3h, b3, y2T, xfT, nullptr, 128, 256, 0, 1);
  gemm1x1_h<<<dim3(8, 16, 4), 256, 0, stream>>>(wqh, bq, xfT, qT,  nullptr, 256, 256, 0, 0);
  gemm1x1_h<<<dim3(8, 16, 4), 256, 0, stream>>>(wkh, bk, xfT, kT,  nullptr, 256, 256, 0, 0);
  gemm1x1_h<<<dim3(8, 16, 4), 256, 0, stream>>>(wvh, bv, xfT, nullptr, vN,  256, 256, 1, 0);
  conv3x3_mfma<<<dim3(8, 16, 4), 256, 0, stream>>>(xfT, wA1h, bb1, t1T, nullptr, 0);
  conv3x3_mfma<<<dim3(8, 16, 4), 256, 0, stream>>>(t1T, wA2h, bb2, nullptr, out, 1);
  attn_rowstats_part<<<dim3(8, 64, 4), 256, 0, stream>>>(kT, qT, Mp, Zp);
  reduce_mz<<<128, 256, 0, stream>>>(Mp, Zp, Mrow, Zrow);
  attn_pass2<<<dim3(8, 64), 256, 0, stream>>>(kT, qT, vN, Mrow, Zrow,
                                              alpha, beta, out);
}

// Round 11
// 549.588 us; speedup vs baseline: 1.3940x; 1.0076x over previous
//
#include <hip/hip_runtime.h>
#include <cstdint>

// AttCM R10: consolidation. pass2 = R6-exact (best of 5 structural variants,
// all 275-284us: pipe-sum-bound). rowstats reworked: wave <-> t-slice (16t),
// all 64 K-rows in regs per wave -> Q LDS reads 32->8 per wave-iter (was 4x
// redundant). QKV = one fused gemm (weights contiguous; grid z routes q/k/v).
// Shapes: B=8, C=256, HW=4096.

#define HW 4096
#define NB 8

typedef __attribute__((ext_vector_type(8))) _Float16 half8;    // 8 fp16 = 4 VGPR
typedef __attribute__((ext_vector_type(4))) float f32x4;       // MFMA C/D

static __device__ __forceinline__ unsigned short f2h(float x) {
  _Float16 h = (_Float16)x;
  return __builtin_bit_cast(unsigned short, h);
}

// ---------------- 1x1 weights fp32 -> fp16, all six packed ----------------
__global__ __launch_bounds__(256) void wcvt6(
    const float* __restrict__ w1, const float* __restrict__ w2,
    const float* __restrict__ w3, const float* __restrict__ wq,
    const float* __restrict__ wk, const float* __restrict__ wv,
    unsigned short* __restrict__ dst) {
  int i = blockIdx.x * 256 + threadIdx.x;
  const float* src; int off;
  if      (i <  16384) { src = w1; off = 0; }
  else if (i <  24576) { src = w2; off = 16384; }
  else if (i <  57344) { src = w3; off = 24576; }
  else if (i < 122880) { src = wq; off = 57344; }
  else if (i < 188416) { src = wk; off = 122880; }
  else                 { src = wv; off = 188416; }
  dst[i] = f2h(src[i - off]);
}

// ---------------- conv weight reorder: OIHW fp32 -> [o][tap][c] fp16 --------
__global__ __launch_bounds__(256) void wreorder(
    const float* __restrict__ w, unsigned short* __restrict__ wA) {
  const int o = blockIdx.x;
  const int c = threadIdx.x;
  const float* wp = w + ((size_t)o * 256 + c) * 9;
#pragma unroll
  for (int tap = 0; tap < 9; tap++)
    wA[((size_t)o * 9 + tap) * 256 + c] = f2h(wp[tap]);
}

// ---------------- fp32 [b][c][p] -> fp16 transposed [b][p][c] ----------------
__global__ __launch_bounds__(256) void transpose_cvt_h(
    const float* __restrict__ in, unsigned short* __restrict__ outT) {
  __shared__ float Ts[64][65];
  const int b  = blockIdx.x;
  const int t0 = blockIdx.y * 64;
  const int c0 = blockIdx.z * 64;
  const int tid = threadIdx.x;
#pragma unroll
  for (int it = 0; it < 4; it++) {
    int id = tid + it * 256;
    int c = id >> 4, f4 = id & 15;
    float4 v = *(const float4*)(in + ((size_t)(b * 256 + c0 + c)) * HW + t0 + f4 * 4);
    Ts[c][f4 * 4 + 0] = v.x; Ts[c][f4 * 4 + 1] = v.y;
    Ts[c][f4 * 4 + 2] = v.z; Ts[c][f4 * 4 + 3] = v.w;
  }
  __syncthreads();
#pragma unroll
  for (int it = 0; it < 2; it++) {
    int id = tid + it * 256;
    int t = id >> 3, ch = id & 7;
    unsigned short h[8];
#pragma unroll
    for (int e = 0; e < 8; e++) h[e] = f2h(Ts[ch * 8 + e][t]);
    int4 pk;
    pk.x = (int)((unsigned)h[0] | ((unsigned)h[1] << 16));
    pk.y = (int)((unsigned)h[2] | ((unsigned)h[3] << 16));
    pk.z = (int)((unsigned)h[4] | ((unsigned)h[5] << 16));
    pk.w = (int)((unsigned)h[6] | ((unsigned)h[7] << 16));
    ((int4*)outT)[((size_t)b * HW + t0 + t) * 32 + (c0 >> 3) + ch] = pk;
  }
}

// ---------------- 1x1 conv: fp16 MFMA GEMM, fused layout epilogue ----------
__global__ __launch_bounds__(256) void gemm1x1_h(
    const unsigned short* __restrict__ Wh,   // fp16 [M][K]
    const float* __restrict__ bias,
    const unsigned short* __restrict__ Xt,   // fp16 [b][4096][K]
    unsigned short* __restrict__ outT,
    unsigned short* __restrict__ outN,
    int K, int M, int mode, int doRelu) {
  __shared__ int4 WsL[64 * 32];
  __shared__ int4 XsL[128 * 8];
  const int b  = blockIdx.x;
  const int p0 = blockIdx.y * 256;
  const int m0 = blockIdx.z * 64;
  const int tid = threadIdx.x;
  const int w = tid >> 6, l = tid & 63;
  const int l4 = l >> 4, l15 = l & 15;
  const int KG  = K >> 3;
  const int kgl = (K >= 256) ? 5 : (K >= 128) ? 4 : 3;
  const int4* Wh4 = (const int4*)Wh;
  const int4* Xt4 = (const int4*)Xt + (size_t)(b * 4096 + p0) * KG;
  for (int id = tid; id < 64 * KG; id += 256) {
    int row = id >> kgl, g = id & (KG - 1);
    WsL[row * KG + (g ^ (row & 7))] = Wh4[(size_t)(m0 + row) * KG + g];
  }
  f32x4 acc[4][4];
#pragma unroll
  for (int i = 0; i < 4; i++)
#pragma unroll
    for (int j = 0; j < 4; j++) acc[i][j] = {0.f, 0.f, 0.f, 0.f};
  const int NCC = K >> 5;
  for (int cc = 0; cc < NCC; cc++) {
    __syncthreads();
#pragma unroll
    for (int it = 0; it < 4; it++) {
      int id = tid + it * 256;
      int p = id >> 2, ch = id & 3;
      XsL[(p >> 1) * 8 + ((((p & 1) << 2) + ch) ^ ((p >> 1) & 7))] =
          Xt4[(size_t)p * KG + cc * 4 + ch];
    }
    __syncthreads();
    half8 a[4], bx[4];
#pragma unroll
    for (int mf = 0; mf < 4; mf++) {
      int m = mf * 16 + l15;
      a[mf] = ((const half8*)WsL)[m * KG + ((cc * 4 + l4) ^ (m & 7))];
    }
#pragma unroll
    for (int nf = 0; nf < 4; nf++) {
      int p = w * 64 + nf * 16 + l15;
      bx[nf] = ((const half8*)XsL)[(p >> 1) * 8 + ((((p & 1) << 2) + l4) ^ ((p >> 1) & 7))];
    }
#pragma unroll
    for (int mf = 0; mf < 4; mf++)
#pragma unroll
      for (int nf = 0; nf < 4; nf++)
        acc[mf][nf] = __builtin_amdgcn_mfma_f32_16x16x32_f16(a[mf], bx[nf], acc[mf][nf], 0, 0, 0);
  }
#pragma unroll
  for (int mf = 0; mf < 4; mf++) {
    const int mrow = m0 + mf * 16 + l4 * 4;
    const f32x4 bv = *(const f32x4*)(bias + mrow);
#pragma unroll
    for (int nf = 0; nf < 4; nf++) {
      const int p = p0 + w * 64 + nf * 16 + l15;
      float vr[4];
#pragma unroll
      for (int r = 0; r < 4; r++) {
        float v = acc[mf][nf][r] + bv[r];
        if (doRelu) v = fmaxf(v, 0.0f);
        vr[r] = v;
      }
      if (mode == 0) {
        unsigned long long pk = (unsigned long long)f2h(vr[0]) |
                                ((unsigned long long)f2h(vr[1]) << 16) |
                                ((unsigned long long)f2h(vr[2]) << 32) |
                                ((unsigned long long)f2h(vr[3]) << 48);
        *(unsigned long long*)(outT + ((size_t)b * 4096 + p) * M + mrow) = pk;
      } else {
#pragma unroll
        for (int r = 0; r < 4; r++)
          outN[((size_t)(b * M + mrow + r)) * 4096 + p] = f2h(vr[r]);
      }
    }
  }
}

// ---------------- fused QKV gemm: M=768 stacked weights, routed epilogue ----
// blockIdx.z in 0..11: sel = z>>2 (0=q,1=k,2=v), m0 = (z&3)*64.
__global__ __launch_bounds__(256) void gemm_qkv(
    const unsigned short* __restrict__ W768,  // fp16 [768][256] (wq|wk|wv)
    const float* __restrict__ bq, const float* __restrict__ bk,
    const float* __restrict__ bv_, const unsigned short* __restrict__ Xt,
    unsigned short* __restrict__ qT, unsigned short* __restrict__ kTo,
    unsigned short* __restrict__ vN) {
  __shared__ int4 WsL[64 * 32];
  __shared__ int4 XsL[128 * 8];
  const int b  = blockIdx.x;
  const int p0 = blockIdx.y * 256;
  const int z  = blockIdx.z;
  const int sel = z >> 2;
  const int m0 = (z & 3) * 64;
  const float* bias = (sel == 0) ? bq : (sel == 1) ? bk : bv_;
  const int tid = threadIdx.x;
  const int w = tid >> 6, l = tid & 63;
  const int l4 = l >> 4, l15 = l & 15;
  const int4* Wh4 = (const int4*)W768 + (size_t)sel * 256 * 32;
  const int4* Xt4 = (const int4*)Xt + (size_t)(b * 4096 + p0) * 32;
  for (int id = tid; id < 64 * 32; id += 256) {
    int row = id >> 5, g = id & 31;
    WsL[row * 32 + (g ^ (row & 7))] = Wh4[(size_t)(m0 + row) * 32 + g];
  }
  f32x4 acc[4][4];
#pragma unroll
  for (int i = 0; i < 4; i++)
#pragma unroll
    for (int j = 0; j < 4; j++) acc[i][j] = {0.f, 0.f, 0.f, 0.f};
  for (int cc = 0; cc < 8; cc++) {
    __syncthreads();
#pragma unroll
    for (int it = 0; it < 4; it++) {
      int id = tid + it * 256;
      int p = id >> 2, ch = id & 3;
      XsL[(p >> 1) * 8 + ((((p & 1) << 2) + ch) ^ ((p >> 1) & 7))] =
          Xt4[(size_t)p * 32 + cc * 4 + ch];
    }
    __syncthreads();
    half8 a[4], bx[4];
#pragma unroll
    for (int mf = 0; mf < 4; mf++) {
      int m = mf * 16 + l15;
      a[mf] = ((const half8*)WsL)[m * 32 + ((cc * 4 + l4) ^ (m & 7))];
    }
#pragma unroll
    for (int nf = 0; nf < 4; nf++) {
      int p = w * 64 + nf * 16 + l15;
      bx[nf] = ((const half8*)XsL)[(p >> 1) * 8 + ((((p & 1) << 2) + l4) ^ ((p >> 1) & 7))];
    }
#pragma unroll
    for (int mf = 0; mf < 4; mf++)
#pragma unroll
      for (int nf = 0; nf < 4; nf++)
        acc[mf][nf] = __builtin_amdgcn_mfma_f32_16x16x32_f16(a[mf], bx[nf], acc[mf][nf], 0, 0, 0);
  }
  unsigned short* outT = (sel == 0) ? qT : kTo;
#pragma unroll
  for (int mf = 0; mf < 4; mf++) {
    const int mrow = m0 + mf * 16 + l4 * 4;
    const f32x4 bvv = *(const f32x4*)(bias + mrow);
#pragma unroll
    for (int nf = 0; nf < 4; nf++) {
      const int p = p0 + w * 64 + nf * 16 + l15;
      float vr[4];
#pragma unroll
      for (int r = 0; r < 4; r++) vr[r] = acc[mf][nf][r] + bvv[r];
      if (sel < 2) {
        unsigned long long pk = (unsigned long long)f2h(vr[0]) |
                                ((unsigned long long)f2h(vr[1]) << 16) |
                                ((unsigned long long)f2h(vr[2]) << 32) |
                                ((unsigned long long)f2h(vr[3]) << 48);
        *(unsigned long long*)(outT + ((size_t)b * 4096 + p) * 256 + mrow) = pk;
      } else {
#pragma unroll
        for (int r = 0; r < 4; r++)
          vN[((size_t)(b * 256 + mrow + r)) * 4096 + p] = f2h(vr[r]);
      }
    }
  }
}

// ---------------- 3x3 conv, fp16 MFMA implicit GEMM (unchanged) ------------
__global__ __launch_bounds__(256, 2) void conv3x3_mfma(
    const unsigned short* __restrict__ inT,
    const unsigned short* __restrict__ wA,
    const float* __restrict__ bias,
    unsigned short* __restrict__ outT,
    float* __restrict__ outN,
    int mode) {
  __shared__ int4 wS[2304];
  __shared__ int4 inS[1584];
  const int b  = blockIdx.x;
  const int y0 = blockIdx.y * 4;
  const int o0 = blockIdx.z * 64;
  const int tid = threadIdx.x;
  const int w = tid >> 6, l = tid & 63;
  const int l4 = l >> 4, l15 = l & 15;
  const int4* inT4 = (const int4*)inT + (size_t)b * 4096 * 32;
  const int4* wA4  = (const int4*)wA;
  f32x4 acc[4][4];
#pragma unroll
  for (int i = 0; i < 4; i++)
#pragma unroll
    for (int j = 0; j < 4; j++) acc[i][j] = {0.f, 0.f, 0.f, 0.f};

  for (int c0 = 0; c0 < 256; c0 += 32) {
    __syncthreads();
#pragma unroll
    for (int it = 0; it < 9; it++) {
      int id = it * 256 + tid;
      int ch = id & 3;
      int r  = id >> 2;
      int tap = r % 9, ol = r / 9;
      int sbw = tap * 32 + (ol >> 1);
      int slot = (4 * (ol & 1) + ch) ^ (sbw & 7);
      wS[sbw * 8 + slot] = wA4[((size_t)(o0 + ol) * 9 + tap) * 32 + (c0 >> 3) + ch];
    }
#pragma unroll
    for (int it = 0; it < 6; it++) {
      int ch = tid & 3;
      int col = tid >> 2;
      int yimg = y0 + it - 1;
      int4 v = {0, 0, 0, 0};
      if (yimg >= 0 && yimg < 64)
        v = inT4[(size_t)(yimg * 64 + col) * 32 + (c0 >> 3) + ch];
      int cl = col + 1;
      int sb = it * 33 + (cl >> 1);
      int slot = (4 * (cl & 1) + ch) ^ (sb & 7);
      inS[sb * 8 + slot] = v;
    }
    if (tid < 48) {
      int row = tid >> 3;
      int cl = ((tid >> 2) & 1) ? 65 : 0;
      int ch = tid & 3;
      int sb = row * 33 + (cl >> 1);
      int slot = (4 * (cl & 1) + ch) ^ (sb & 7);
      inS[sb * 8 + slot] = {0, 0, 0, 0};
    }
    __syncthreads();
#pragma unroll
    for (int tap = 0; tap < 9; tap++) {
      const int dy = tap / 3, dx = tap % 3;
      half8 a[4], bf[4];
#pragma unroll
      for (int mf = 0; mf < 4; mf++) {
        int oc = mf * 16 + l15;
        int sbw = tap * 32 + (oc >> 1);
        a[mf] = ((const half8*)wS)[sbw * 8 + ((4 * (oc & 1) + l4) ^ (sbw & 7))];
      }
#pragma unroll
      for (int nf = 0; nf < 4; nf++) {
        int cl = nf * 16 + l15 + dx;
        int row = w + dy;
        int sb = row * 33 + (cl >> 1);
        bf[nf] = ((const half8*)inS)[sb * 8 + ((4 * (cl & 1) + l4) ^ (sb & 7))];
      }
#pragma unroll
      for (int mf = 0; mf < 4; mf++)
#pragma unroll
        for (int nf = 0; nf < 4; nf++)
          acc[mf][nf] = __builtin_amdgcn_mfma_f32_16x16x32_f16(a[mf], bf[nf], acc[mf][nf], 0, 0, 0);
    }
  }
  const int p_base = (y0 + w) * 64;
#pragma unroll
  for (int mf = 0; mf < 4; mf++) {
    const int ocb = o0 + mf * 16 + l4 * 4;
    const f32x4 bv = *(const f32x4*)(bias + ocb);
#pragma unroll
    for (int nf = 0; nf < 4; nf++) {
      const int p = p_base + nf * 16 + l15;
      if (mode == 0) {
        unsigned short h[4];
#pragma unroll
        for (int r = 0; r < 4; r++)
          h[r] = f2h(fmaxf(acc[mf][nf][r] + bv[r], 0.0f));
        unsigned long long pk = (unsigned long long)h[0] |
                                ((unsigned long long)h[1] << 16) |
                                ((unsigned long long)h[2] << 32) |
                                ((unsigned long long)h[3] << 48);
        *(unsigned long long*)(outT + ((size_t)b * 4096 + p) * 256 + ocb) = pk;
      } else {
#pragma unroll
        for (int r = 0; r < 4; r++)
          outN[((size_t)(b * 256 + ocb + r)) * HW + p] = acc[mf][nf][r] + bv[r];
      }
    }
  }
}

// ---------------- attention pass 1a: t-sliced waves, K fully in regs --------
// Block: 64 r x 1024 t (quarter q). Wave w owns t-slice w*16 within each
// 64-t iter and ALL 64 K-rows in regs (afr[4][8], loaded once). Q LDS reads:
// 8/wave-iter (was 32). Partials: 16 per row (4 quarters x 4 waves).
__global__ __launch_bounds__(256) void attn_rowstats_part(
    const unsigned short* __restrict__ kT, const unsigned short* __restrict__ qT,
    float* __restrict__ Mp, float* __restrict__ Zp) {
  __shared__ int4 qs4[64][32];   // 32KB [t][c-granule], swizzled
  const int b  = blockIdx.x;
  const int r0 = blockIdx.y * 64;
  const int q  = blockIdx.z;
  const int tid = threadIdx.x;
  const int w = tid >> 6, l = tid & 63;
  const int l4 = l >> 4, l15 = l & 15;
  const int4* qT4 = (const int4*)qT + (size_t)b * HW * 32;
  const half8* kT8 = (const half8*)kT + ((size_t)b * HW + r0) * 32;
  half8 afr[4][8];               // all 64 rows: [mfl][g]
#pragma unroll
  for (int mfl = 0; mfl < 4; mfl++)
#pragma unroll
    for (int g = 0; g < 8; g++)
      afr[mfl][g] = kT8[(size_t)(mfl * 16 + l15) * 32 + g * 4 + l4];
  float m[4][4], z[4][4];        // [mfl][reg]
#pragma unroll
  for (int i = 0; i < 4; i++)
#pragma unroll
    for (int j = 0; j < 4; j++) { m[i][j] = -1e30f; z[i][j] = 0.0f; }
  for (int t0 = q * 1024; t0 < q * 1024 + 1024; t0 += 64) {
    __syncthreads();
#pragma unroll
    for (int it = 0; it < 8; it++) {
      int id = tid + it * 256;
      int row = id >> 5, ch = id & 31;
      qs4[row][ch ^ (row & 7)] = qT4[(size_t)(t0 + row) * 32 + ch];
    }
    __syncthreads();
    f32x4 acc[4] = {{0.f,0.f,0.f,0.f},{0.f,0.f,0.f,0.f},
                    {0.f,0.f,0.f,0.f},{0.f,0.f,0.f,0.f}};
    const int t = w * 16 + l15;  // this wave's t-slice
#pragma unroll
    for (int g = 0; g < 8; g++) {
      half8 bq = ((const half8*)qs4)[t * 32 + ((g * 4 + l4) ^ (t & 7))];
#pragma unroll
      for (int mfl = 0; mfl < 4; mfl++)
        acc[mfl] = __builtin_amdgcn_mfma_f32_16x16x32_f16(afr[mfl][g], bq, acc[mfl], 0, 0, 0);
    }
#pragma unroll
    for (int mfl = 0; mfl < 4; mfl++)
#pragma unroll
      for (int r = 0; r < 4; r++) {
        float sv = acc[mfl][r];
        if (sv > m[mfl][r]) { z[mfl][r] *= __expf(m[mfl][r] - sv); m[mfl][r] = sv; }
        z[mfl][r] += __expf(sv - m[mfl][r]);
      }
  }
  // merge across the 16 lanes (l15) holding different t of the same rows
#pragma unroll
  for (int mfl = 0; mfl < 4; mfl++)
#pragma unroll
    for (int r = 0; r < 4; r++) {
      for (int off = 1; off < 16; off <<= 1) {
        float mo = __shfl_xor(m[mfl][r], off, 16);
        float zo = __shfl_xor(z[mfl][r], off, 16);
        float mn = fmaxf(m[mfl][r], mo);
        z[mfl][r] = z[mfl][r] * __expf(m[mfl][r] - mn) + zo * __expf(mo - mn);
        m[mfl][r] = mn;
      }
    }
  if (l15 == 0) {
#pragma unroll
    for (int mfl = 0; mfl < 4; mfl++)
#pragma unroll
      for (int r = 0; r < 4; r++) {
        int rr = r0 + mfl * 16 + l4 * 4 + r;
        Mp[((size_t)b * HW + rr) * 16 + q * 4 + w] = m[mfl][r];
        Zp[((size_t)b * HW + rr) * 16 + q * 4 + w] = z[mfl][r];
      }
  }
}

// ---------------- attention pass 1b: merge 16 partials ----------------------
__global__ __launch_bounds__(256) void reduce_mz(
    const float* __restrict__ Mp, const float* __restrict__ Zp,
    float* __restrict__ Mrow, float* __restrict__ Zrow) {
  int i = blockIdx.x * 256 + threadIdx.x;      // 0 .. 8*4096-1
  float mq[16], zq[16];
#pragma unroll
  for (int j = 0; j < 4; j++) {
    float4 mv = *(const float4*)(Mp + (size_t)i * 16 + j * 4);
    float4 zv = *(const float4*)(Zp + (size_t)i * 16 + j * 4);
    mq[j*4+0] = mv.x; mq[j*4+1] = mv.y; mq[j*4+2] = mv.z; mq[j*4+3] = mv.w;
    zq[j*4+0] = zv.x; zq[j*4+1] = zv.y; zq[j*4+2] = zv.z; zq[j*4+3] = zv.w;
  }
  float M = mq[0];
#pragma unroll
  for (int j = 1; j < 16; j++) M = fmaxf(M, mq[j]);
  float Z = 0.0f;
#pragma unroll
  for (int j = 0; j < 16; j++) Z += zq[j] * __expf(mq[j] - M);
  Mrow[i] = M;
  Zrow[i] = 1.0f / Z;
}

// ---------------- attention pass 2 (R6-exact): bp-once + early V preload ----
__global__ __launch_bounds__(256, 2) void attn_pass2(
    const unsigned short* __restrict__ kT, const unsigned short* __restrict__ qT,
    const unsigned short* __restrict__ vB, const float* __restrict__ Mrow,
    const float* __restrict__ Zrow, const float* __restrict__ alphap,
    const float* __restrict__ betap, float* __restrict__ out) {
  __shared__ int4 qs4[64][32];      // 32KB Q [t][c-granule], swizzled
  __shared__ int4 ps4[2][64][16];   // 2x16KB P [t][r-granule], swizzled
  const int b  = blockIdx.x;
  const int t0 = blockIdx.y * 64;
  const int tid = threadIdx.x;
  const int w = tid >> 6, l = tid & 63;
  const int l4 = l >> 4, l15 = l & 15;
  const int4*  qT4 = (const int4*)qT + ((size_t)b * HW + t0) * 32;
  const half8* kT8 = (const half8*)kT + (size_t)b * HW * 32;
  const half8* vB8 = (const half8*)vB + (size_t)b * 256 * 512;
  const float* Mb = Mrow + (size_t)b * HW;
  const float* Zb = Zrow + (size_t)b * HW;
#pragma unroll
  for (int it = 0; it < 8; it++) {
    int id = tid + it * 256;
    int row = id >> 5, ch = id & 31;
    qs4[row][ch ^ (row & 7)] = qT4[(size_t)row * 32 + ch];
  }
  f32x4 acc_o[4][4];
#pragma unroll
  for (int i = 0; i < 4; i++)
#pragma unroll
    for (int j = 0; j < 4; j++) acc_o[i][j] = {0.f, 0.f, 0.f, 0.f};
  __syncthreads();

#pragma unroll 1
  for (int iter = 0; iter < 32; iter++) {
    const int r0 = iter * 128;
    int4* psb = &ps4[iter & 1][0][0];
    half8 ak0[8], ak1[8];
#pragma unroll
    for (int g = 0; g < 8; g++) {
      ak0[g] = kT8[(size_t)(r0 + w * 32 + l15) * 32 + g * 4 + l4];
      ak1[g] = kT8[(size_t)(r0 + w * 32 + 16 + l15) * 32 + g * 4 + l4];
    }
    f32x4 acc_s[2][4];
#pragma unroll
    for (int i = 0; i < 2; i++)
#pragma unroll
      for (int j = 0; j < 4; j++) acc_s[i][j] = {0.f, 0.f, 0.f, 0.f};
#pragma unroll
    for (int g = 0; g < 8; g++) {
      half8 bq[4];
#pragma unroll
      for (int nf = 0; nf < 4; nf++) {
        int t = nf * 16 + l15;
        bq[nf] = ((const half8*)qs4)[t * 32 + ((g * 4 + l4) ^ (t & 7))];
      }
#pragma unroll
      for (int nf = 0; nf < 4; nf++) {
        acc_s[0][nf] = __builtin_amdgcn_mfma_f32_16x16x32_f16(ak0[g], bq[nf], acc_s[0][nf], 0, 0, 0);
        acc_s[1][nf] = __builtin_amdgcn_mfma_f32_16x16x32_f16(ak1[g], bq[nf], acc_s[1][nf], 0, 0, 0);
      }
    }
    half8 avr[4][4];   // [cc4][ks]
#pragma unroll
    for (int cc4 = 0; cc4 < 2; cc4++) {
      const int c = cc4 * 64 + w * 16 + l15;
#pragma unroll
      for (int ks = 0; ks < 4; ks++)
        avr[cc4][ks] = vB8[(size_t)c * 512 + (r0 >> 3) + ks * 4 + l4];
    }
#pragma unroll
    for (int mfl = 0; mfl < 2; mfl++) {
      int rbase = r0 + w * 32 + mfl * 16 + l4 * 4;
      f32x4 Mv = *(const f32x4*)(Mb + rbase);
      f32x4 Zv = *(const f32x4*)(Zb + rbase);
      int slot = w * 8 + mfl * 4 + l4;
#pragma unroll
      for (int nf = 0; nf < 4; nf++) {
        int t = nf * 16 + l15;
        unsigned lo = (unsigned)f2h(__expf(acc_s[mfl][nf][0] - Mv[0]) * Zv[0])
                    | ((unsigned)f2h(__expf(acc_s[mfl][nf][1] - Mv[1]) * Zv[1]) << 16);
        unsigned hi = (unsigned)f2h(__expf(acc_s[mfl][nf][2] - Mv[2]) * Zv[2])
                    | ((unsigned)f2h(__expf(acc_s[mfl][nf][3] - Mv[3]) * Zv[3]) << 16);
        int ch = slot >> 1;
        int fslot = ((ch ^ (t & 7)) << 1) | (slot & 1);
        ((unsigned long long*)psb)[(size_t)t * 32 + fslot] =
            ((unsigned long long)hi << 32) | (unsigned long long)lo;
      }
    }
    __syncthreads();
#pragma unroll
    for (int cc4 = 2; cc4 < 4; cc4++) {
      const int c = cc4 * 64 + w * 16 + l15;
#pragma unroll
      for (int ks = 0; ks < 4; ks++)
        avr[cc4][ks] = vB8[(size_t)c * 512 + (r0 >> 3) + ks * 4 + l4];
    }
#pragma unroll
    for (int ks = 0; ks < 4; ks++) {
#pragma unroll
      for (int nf = 0; nf < 4; nf++) {
        int t = nf * 16 + l15;
        half8 bp = ((const half8*)psb)[t * 16 + ((ks * 4 + l4) ^ (t & 7))];
#pragma unroll
        for (int cc4 = 0; cc4 < 4; cc4++)
          acc_o[cc4][nf] = __builtin_amdgcn_mfma_f32_16x16x32_f16(avr[cc4][ks], bp, acc_o[cc4][nf], 0, 0, 0);
      }
    }
  }
  const float alpha = alphap[0], beta = betap[0];
#pragma unroll
  for (int cc4 = 0; cc4 < 4; cc4++) {
    int cbase = cc4 * 64 + w * 16 + l4 * 4;
#pragma unroll
    for (int nf = 0; nf < 4; nf++) {
      int t = t0 + nf * 16 + l15;
#pragma unroll
      for (int r = 0; r < 4; r++) {
        size_t idx = ((size_t)(b * 256 + cbase + r)) * HW + t;
        out[idx] = alpha * out[idx] + beta * acc_o[cc4][nf][r];
      }
    }
  }
}

extern "C" void kernel_launch(void* const* d_in, const int* in_sizes, int n_in,
                              void* d_out, int out_size, void* d_ws, size_t ws_size,
                              hipStream_t stream) {
  (void)in_sizes; (void)n_in; (void)out_size; (void)ws_size;
  const float* x   = (const float*)d_in[0];
  const float* w1  = (const float*)d_in[1];
  const float* b1  = (const float*)d_in[2];
  const float* w2  = (const float*)d_in[3];
  const float* b2  = (const float*)d_in[4];
  const float* w3  = (const float*)d_in[5];
  const float* b3  = (const float*)d_in[6];
  const float* wb1 = (const float*)d_in[7];
  const float* bb1 = (const float*)d_in[8];
  const float* wb2 = (const float*)d_in[9];
  const float* bb2 = (const float*)d_in[10];
  const float* wq  = (const float*)d_in[11];
  const float* bq  = (const float*)d_in[12];
  const float* wk  = (const float*)d_in[13];
  const float* bk  = (const float*)d_in[14];
  const float* wv  = (const float*)d_in[15];
  const float* bv  = (const float*)d_in[16];
  const float* alpha = (const float*)d_in[17];
  const float* beta  = (const float*)d_in[18];
  float* out = (float*)d_out;

  const size_t SZH = (size_t)NB * 4096 * 256;   // 8,388,608 halves = 16MB
  unsigned short* wsh = (unsigned short*)d_ws;
  unsigned short* xh  = wsh;
  unsigned short* xfT = wsh + SZH;
  unsigned short* qT  = wsh + 2 * SZH;
  unsigned short* kT  = wsh + 3 * SZH;
  unsigned short* vN  = wsh + 4 * SZH;
  unsigned short* y1T = wsh + 5 * SZH;
  unsigned short* y2T = y1T + SZH / 4;
  unsigned short* t1T = wsh + 5 * SZH;
  float* Mrow = (float*)(wsh + 6 * SZH);
  float* Zrow = Mrow + (size_t)NB * HW;
  float* Mp   = Zrow + (size_t)NB * HW;         // [B*HW*16] partials
  float* Zp   = Mp + (size_t)NB * HW * 16;
  unsigned short* wh   = (unsigned short*)(Zp + (size_t)NB * HW * 16);
  unsigned short* w1h  = wh;
  unsigned short* w2h  = wh + 16384;
  unsigned short* w3h  = wh + 24576;
  unsigned short* wqh  = wh + 57344;            // [768][256] contiguous q|k|v
  unsigned short* wA1h = wh + 253952;
  unsigned short* wA2h = wA1h + (size_t)256 * 9 * 256;

  wcvt6<<<992, 256, 0, stream>>>(w1, w2, w3, wq, wk, wv, wh);
  wreorder<<<256, 256, 0, stream>>>(wb1, wA1h);
  wreorder<<<256, 256, 0, stream>>>(wb2, wA2h);
  transpose_cvt_h<<<dim3(8, 64, 4), 256, 0, stream>>>(x, xh);
  gemm1x1_h<<<dim3(8, 16, 1), 256, 0, stream>>>(w1h, b1, xh,  y1T, nullptr, 256,  64, 0, 1);
  gemm1x1_h<<<dim3(8, 16, 2), 256, 0, stream>>>(w2h, b2, y1T, y2T, nullptr,  64, 128, 0, 1);
  gemm1x1_h<<<dim3(8, 16, 4), 256, 0, stream>>>(w3h, b3, y2T, xfT, nullptr, 128, 256, 0, 1);
  gemm_qkv<<<dim3(8, 16, 12), 256, 0, stream>>>(wqh, bq, bk, bv, xfT, qT, kT, vN);
  conv3x3_mfma<<<dim3(8, 16, 4), 256, 0, stream>>>(xfT, wA1h, bb1, t1T, nullptr, 0);
  conv3x3_mfma<<<dim3(8, 16, 4), 256, 0, stream>>>(t1T, wA2h, bb2, nullptr, out, 1);
  attn_rowstats_part<<<dim3(8, 64, 4), 256, 0, stream>>>(kT, qT, Mp, Zp);
  reduce_mz<<<128, 256, 0, stream>>>(Mp, Zp, Mrow, Zrow);
  attn_pass2<<<dim3(8, 64), 256, 0, stream>>>(kT, qT, vN, Mrow, Zrow,
                                              alpha, beta, out);
}